// Round 4
// baseline (1145.967 us; speedup 1.0000x reference)
//
#include <hip/hip_runtime.h>
#include <math.h>

constexpr float LEAKY = 0.2f;

__device__ __forceinline__ float4 ldf4(const float* p){ return *reinterpret_cast<const float4*>(p); }
__device__ __forceinline__ void stf4(float* p, float4 v){ *reinterpret_cast<float4*>(p) = v; }
__device__ __forceinline__ float dot4(float4 a, float4 b){ return a.x*b.x + a.y*b.y + a.z*b.z + a.w*b.w; }
__device__ __forceinline__ float4 fma4(float s, float4 b, float4 acc){
    acc.x += s*b.x; acc.y += s*b.y; acc.z += s*b.z; acc.w += s*b.w; return acc;
}
__device__ __forceinline__ float lrelu(float f){ return f > 0.f ? f : LEAKY*f; }
__device__ __forceinline__ float4 lrelu4(float s, float4 t){
    float4 r; r.x = lrelu(s+t.x); r.y = lrelu(s+t.y); r.z = lrelu(s+t.z); r.w = lrelu(s+t.w); return r;
}
__device__ __forceinline__ float vmax4(float4 v){ return fmaxf(fmaxf(v.x,v.y), fmaxf(v.z,v.w)); }
__device__ __forceinline__ float vsum4(float4 v){ return v.x+v.y+v.z+v.w; }
__device__ __forceinline__ float4 exp4(float4 a, float mx){
    float4 r; r.x = __expf(a.x-mx); r.y = __expf(a.y-mx); r.z = __expf(a.z-mx); r.w = __expf(a.w-mx); return r;
}

// ws layout (floats): wv[12*64]@0 | WspT0[12*64]@768 | WspT1[5*64]@1536 | WtpT0[32*64]@1856 | WtpT1[16*64]@3904
__global__ void prep_kernel(const float* __restrict__ W,
    const float* a0, const float* a1, const float* a2,  const float* a3,
    const float* a4, const float* a5, const float* a6,  const float* a7,
    const float* a8, const float* a9, const float* a10, const float* a11,
    const float* __restrict__ Wsp0, const float* __restrict__ Wsp1,
    const float* __restrict__ Wtp0, const float* __restrict__ Wtp1,
    float* __restrict__ ws)
{
    int blk = blockIdx.x, t = threadIdx.x;
    if (blk < 12) {
        const float* as[12] = {a0,a1,a2,a3,a4,a5,a6,a7,a8,a9,a10,a11};
        const float* a = as[blk];
        float s = 0.f;
        #pragma unroll
        for (int h = 0; h < 128; ++h) s += W[t*128 + h] * a[h];
        ws[blk*64 + t] = s;
    } else if (blk == 12) {
        for (int i = t; i < 768; i += 64) { int k = i >> 6, c = i & 63; ws[768 + i] = Wsp0[c*12 + k]; }
    } else if (blk == 13) {
        for (int i = t; i < 320; i += 64) { int k = i >> 6, c = i & 63; ws[1536 + i] = Wsp1[c*5 + k]; }
    } else if (blk == 14) {
        for (int i = t; i < 2048; i += 64) { int k = i >> 6, c = i & 63; ws[1856 + i] = Wtp0[c*32 + k]; }
    } else {
        for (int i = t; i < 1024; i += 64) { int k = i >> 6, c = i & 63; ws[3904 + i] = Wtp1[c*16 + k]; }
    }
}

// ================== TEMPORAL: 6400 graphs of 64 nodes, 512 threads ==================
__global__ __launch_bounds__(512, 4)
void temporal_kernel(const float* __restrict__ src, const float* __restrict__ wvg,
                     const float* __restrict__ WpT0, const float* __restrict__ WpT1,
                     const float* __restrict__ b0, const float* __restrict__ b1,
                     float* __restrict__ out, int nwg8)
{
    __shared__ __align__(16) float Rx0[4352];   // x0[64][68]; tenants after x0 dies
    __shared__ __align__(16) float RA0[4352];   // A0/fusion [64][68]
    __shared__ __align__(16) float RPR[2304];   // P0T[32][68] -> x1[32][68] -> M1[64][36] -> M2[64][20]
    __shared__ __align__(16) float RS0[2304];   // S0[64][36]
    __shared__ __align__(16) float sv[64], tv[64], ua[64], va[64], rxa[16], rsa[16];

    float* x0  = Rx0;
    float* A1  = Rx0;          // [32][36]
    float* A1T = Rx0 + 1152;   // [32][36]
    float* P1T = Rx0 + 2304;   // [16][36]
    float* S1  = Rx0 + 2880;   // [32][20]
    float* S1T = Rx0 + 3520;   // [16][36]
    float* A2T = Rx0 + 2304;   // [16][20]  (after P1T dead)
    float* S01 = Rx0;          // [64][20]  (after A1/A1T dead)
    float* A0  = RA0;
    float* P0T = RPR;          // [32][68]
    float* x1  = RPR;          // [32][68]
    float* M1  = RPR;          // [64][36]
    float* M2  = RPR;          // [64][20]
    float* S0  = RS0;          // [64][36]

    const int t = threadIdx.x;
    const int g = (blockIdx.x & 7) * nwg8 + (blockIdx.x >> 3);
    const int b = g / 25, inner = g - b*25;
    const float* srcb = src + (size_t)b*102400 + inner;  // + c*1600 + r*25  (inner = joint, stride 1)

    float facc[8][4];   // fusion accumulator (threads 0..127), lives G2a..G5

    // ---- L: load x0[r][c], stride 68 ----
    for (int i = t; i < 1024; i += 512) {
        int r = i & 63, c0 = (i >> 6) << 2;
        float4 v;
        v.x = srcb[(c0+0)*1600 + r*25];
        v.y = srcb[(c0+1)*1600 + r*25];
        v.z = srcb[(c0+2)*1600 + r*25];
        v.w = srcb[(c0+3)*1600 + r*25];
        stf4(&x0[r*68 + c0], v);
    }
    __syncthreads();

    // ---- P0: s0/t0 dots || P0T = (x0@Wp0)^T ----
    if (t < 128) {
        int which = t >> 6, p = t & 63;
        const float* w = wvg + which*64;
        float a = 0.f;
        #pragma unroll
        for (int c4 = 0; c4 < 16; ++c4) a += dot4(ldf4(&x0[p*68 + 4*c4]), ldf4(&w[4*c4]));
        if (which) tv[p] = a; else sv[p] = a;
    } else if (t < 256) {
        int tp = t - 128, k0 = tp & 7, m0 = tp >> 3;
        float acc[4][4] = {};
        #pragma unroll
        for (int c4 = 0; c4 < 16; ++c4) {
            float4 av[4], bv[4];
            #pragma unroll
            for (int i = 0; i < 4; ++i) av[i] = ldf4(&WpT0[(k0+8*i)*64 + 4*c4]);
            #pragma unroll
            for (int j = 0; j < 4; ++j) bv[j] = ldf4(&x0[(m0+16*j)*68 + 4*c4]);
            #pragma unroll
            for (int i = 0; i < 4; ++i)
                #pragma unroll
                for (int j = 0; j < 4; ++j) acc[i][j] += dot4(av[i], bv[j]);
        }
        #pragma unroll
        for (int i = 0; i < 4; ++i)
            #pragma unroll
            for (int j = 0; j < 4; ++j) P0T[(k0+8*i)*68 + m0+16*j] = acc[i][j];
    }
    __syncthreads();

    // ---- P1: A0 = lrelu(s + t^T) ----
    {
        int i = t, p = i >> 4, q4 = i & 15;
        stf4(&A0[p*68 + 4*q4], lrelu4(sv[p], ldf4(&tv[4*q4])));
        i = t + 512; p = i >> 4; q4 = i & 15;
        stf4(&A0[p*68 + 4*q4], lrelu4(sv[p], ldf4(&tv[4*q4])));
    }
    __syncthreads();

    // ---- P2: S0raw[p][k] = A0 row . P0T row + b0 ----
    if (t < 64) {
        int p0 = t & 7, k0 = t >> 3;
        float acc[8][4];
        #pragma unroll
        for (int i = 0; i < 8; ++i)
            #pragma unroll
            for (int j = 0; j < 4; ++j) acc[i][j] = b0[k0+8*j];
        #pragma unroll
        for (int m4 = 0; m4 < 16; ++m4) {
            float4 av[8], bv[4];
            #pragma unroll
            for (int i = 0; i < 8; ++i) av[i] = ldf4(&A0[(p0+8*i)*68 + 4*m4]);
            #pragma unroll
            for (int j = 0; j < 4; ++j) bv[j] = ldf4(&P0T[(k0+8*j)*68 + 4*m4]);
            #pragma unroll
            for (int i = 0; i < 8; ++i)
                #pragma unroll
                for (int j = 0; j < 4; ++j) acc[i][j] += dot4(av[i], bv[j]);
        }
        #pragma unroll
        for (int i = 0; i < 8; ++i)
            #pragma unroll
            for (int j = 0; j < 4; ++j) S0[(p0+8*i)*36 + k0+8*j] = acc[i][j];
    }
    __syncthreads();

    // ---- P3: row softmax S0 ----
    if (t < 64) {
        float4 r[8]; float mx = -1e30f;
        #pragma unroll
        for (int u = 0; u < 8; ++u) { r[u] = ldf4(&S0[t*36 + 4*u]); mx = fmaxf(mx, vmax4(r[u])); }
        float sm = 0.f;
        #pragma unroll
        for (int u = 0; u < 8; ++u) { r[u] = exp4(r[u], mx); sm += vsum4(r[u]); }
        float inv = 1.f/sm;
        #pragma unroll
        for (int u = 0; u < 8; ++u) {
            r[u].x *= inv; r[u].y *= inv; r[u].z *= inv; r[u].w *= inv;
            stf4(&S0[t*36 + 4*u], r[u]);
        }
    }
    __syncthreads();

    // ---- P4: x1[k][c] = sum_p S0[p][k] * x0[p][c]  (4k x 8c tiles) ----
    if (t < 64) {
        int k0 = (t & 7) << 2, c0 = (t >> 3) << 3;
        float4 accA[4] = {}, accB[4] = {};
        #pragma unroll 8
        for (int p = 0; p < 64; ++p) {
            float4 s4 = ldf4(&S0[p*36 + k0]);
            float4 xa = ldf4(&x0[p*68 + c0]);
            float4 xb = ldf4(&x0[p*68 + c0 + 4]);
            accA[0] = fma4(s4.x, xa, accA[0]); accB[0] = fma4(s4.x, xb, accB[0]);
            accA[1] = fma4(s4.y, xa, accA[1]); accB[1] = fma4(s4.y, xb, accB[1]);
            accA[2] = fma4(s4.z, xa, accA[2]); accB[2] = fma4(s4.z, xb, accB[2]);
            accA[3] = fma4(s4.w, xa, accA[3]); accB[3] = fma4(s4.w, xb, accB[3]);
        }
        #pragma unroll
        for (int ki = 0; ki < 4; ++ki) {
            stf4(&x1[(k0+ki)*68 + c0], accA[ki]);
            stf4(&x1[(k0+ki)*68 + c0 + 4], accB[ki]);
        }
    }
    __syncthreads();

    // ---- P5: s1/t1/u/v dots || P1T = (x1@Wp1)^T ----
    if (t < 128) {
        int which = t >> 5, p = t & 31;
        const float* w = wvg + (2+which)*64;
        float a = 0.f;
        #pragma unroll
        for (int c4 = 0; c4 < 16; ++c4) a += dot4(ldf4(&x1[p*68 + 4*c4]), ldf4(&w[4*c4]));
        if (which == 0) sv[p] = a; else if (which == 1) tv[p] = a;
        else if (which == 2) ua[p] = a; else va[p] = a;
    } else if (t < 256) {
        int tp = t - 128, j = tp >> 3, k0 = tp & 7;
        float acc[4] = {};
        #pragma unroll
        for (int c4 = 0; c4 < 16; ++c4) {
            float4 wv4 = ldf4(&WpT1[j*64 + 4*c4]);
            #pragma unroll
            for (int i = 0; i < 4; ++i) acc[i] += dot4(ldf4(&x1[(k0+8*i)*68 + 4*c4]), wv4);
        }
        #pragma unroll
        for (int i = 0; i < 4; ++i) P1T[j*36 + k0+8*i] = acc[i];
    }
    __syncthreads();

    // ---- P6: A1, A1T ----
    {
        int mat = t >> 8, p = (t >> 3) & 31, q4 = t & 7;
        if (mat == 0) stf4(&A1 [p*36 + 4*q4], lrelu4(sv[p], ldf4(&tv[4*q4])));
        else          stf4(&A1T[p*36 + 4*q4], lrelu4(tv[p], ldf4(&sv[4*q4])));
    }
    __syncthreads();

    // ---- G1: M1 = S0 @ A1 (row-dot with A1T) || S1raw = A1@P1 + b1 ----
    if (t < 64) {
        int p0 = t & 7, k0 = t >> 3;
        float acc[8][4] = {};
        #pragma unroll
        for (int m4 = 0; m4 < 8; ++m4) {
            float4 av[8], bv[4];
            #pragma unroll
            for (int i = 0; i < 8; ++i) av[i] = ldf4(&S0[(p0+8*i)*36 + 4*m4]);
            #pragma unroll
            for (int j = 0; j < 4; ++j) bv[j] = ldf4(&A1T[(k0+8*j)*36 + 4*m4]);
            #pragma unroll
            for (int i = 0; i < 8; ++i)
                #pragma unroll
                for (int j = 0; j < 4; ++j) acc[i][j] += dot4(av[i], bv[j]);
        }
        #pragma unroll
        for (int i = 0; i < 8; ++i)
            #pragma unroll
            for (int j = 0; j < 4; ++j) M1[(p0+8*i)*36 + k0+8*j] = acc[i][j];
    } else if (t < 96) {
        int tp = t - 64, m0 = tp & 7, j0 = tp >> 3;
        float acc[4][4];
        #pragma unroll
        for (int i = 0; i < 4; ++i)
            #pragma unroll
            for (int j = 0; j < 4; ++j) acc[i][j] = b1[j0+4*j];
        #pragma unroll
        for (int k4 = 0; k4 < 8; ++k4) {
            float4 av[4], bv[4];
            #pragma unroll
            for (int i = 0; i < 4; ++i) av[i] = ldf4(&A1[(m0+8*i)*36 + 4*k4]);
            #pragma unroll
            for (int j = 0; j < 4; ++j) bv[j] = ldf4(&P1T[(j0+4*j)*36 + 4*k4]);
            #pragma unroll
            for (int i = 0; i < 4; ++i)
                #pragma unroll
                for (int j = 0; j < 4; ++j) acc[i][j] += dot4(av[i], bv[j]);
        }
        #pragma unroll
        for (int i = 0; i < 4; ++i)
            #pragma unroll
            for (int j = 0; j < 4; ++j) S1[(m0+8*i)*20 + j0+4*j] = acc[i][j];
    }
    __syncthreads();

    // ---- G2a: fusion regs = A0 + M1@S0^T || softmax S1 ----
    {
        int fp0 = t & 7, fq0 = t >> 3;
        if (t < 128) {
            #pragma unroll
            for (int i = 0; i < 8; ++i)
                #pragma unroll
                for (int j = 0; j < 4; ++j) facc[i][j] = A0[(fp0+8*i)*68 + fq0+16*j];
            #pragma unroll
            for (int m4 = 0; m4 < 8; ++m4) {
                float4 av[8], bv[4];
                #pragma unroll
                for (int i = 0; i < 8; ++i) av[i] = ldf4(&M1[(fp0+8*i)*36 + 4*m4]);
                #pragma unroll
                for (int j = 0; j < 4; ++j) bv[j] = ldf4(&S0[(fq0+16*j)*36 + 4*m4]);
                #pragma unroll
                for (int i = 0; i < 8; ++i)
                    #pragma unroll
                    for (int j = 0; j < 4; ++j) facc[i][j] += dot4(av[i], bv[j]);
            }
        } else if (t < 160) {
            int m = t - 128;
            float4 r[4]; float mx = -1e30f;
            #pragma unroll
            for (int u = 0; u < 4; ++u) { r[u] = ldf4(&S1[m*20 + 4*u]); mx = fmaxf(mx, vmax4(r[u])); }
            float sm = 0.f;
            #pragma unroll
            for (int u = 0; u < 4; ++u) { r[u] = exp4(r[u], mx); sm += vsum4(r[u]); }
            float inv = 1.f/sm;
            #pragma unroll
            for (int u = 0; u < 4; ++u) {
                r[u].x *= inv; r[u].y *= inv; r[u].z *= inv; r[u].w *= inv;
                stf4(&S1[m*20 + 4*u], r[u]);
            }
        }
    }
    __syncthreads();

    // ---- G2b: S1T || rxa/rsa = S1^T . (u,v) ----
    if (t < 256) {
        for (int i = t; i < 512; i += 256) { int j = i >> 5, m = i & 31; S1T[j*36 + m] = S1[m*20 + j]; }
    } else if (t >= 448 && t < 480) {
        int tp = t - 448, k = tp & 15, which = tp >> 4;
        float a = 0.f;
        #pragma unroll
        for (int n = 0; n < 32; ++n) a += S1[n*20 + k] * (which ? va[n] : ua[n]);
        if (which) rsa[k] = a; else rxa[k] = a;
    }
    __syncthreads();

    // ---- G3: S01 = S0 @ S1 (row-dot with S1T) || A2T build ----
    if (t < 64) {
        int p0 = t & 15, j0 = t >> 4;
        float acc[4][4] = {};
        #pragma unroll
        for (int m4 = 0; m4 < 8; ++m4) {
            float4 av[4], bv[4];
            #pragma unroll
            for (int i = 0; i < 4; ++i) av[i] = ldf4(&S0[(p0+16*i)*36 + 4*m4]);
            #pragma unroll
            for (int j = 0; j < 4; ++j) bv[j] = ldf4(&S1T[(j0+4*j)*36 + 4*m4]);
            #pragma unroll
            for (int i = 0; i < 4; ++i)
                #pragma unroll
                for (int j = 0; j < 4; ++j) acc[i][j] += dot4(av[i], bv[j]);
        }
        #pragma unroll
        for (int i = 0; i < 4; ++i)
            #pragma unroll
            for (int j = 0; j < 4; ++j) S01[(p0+16*i)*20 + j0+4*j] = acc[i][j];
    } else if (t >= 256) {
        int i = t - 256, q = i >> 4, p = i & 15;
        A2T[q*20 + p] = lrelu(rxa[p] + rsa[q]);
    }
    __syncthreads();

    // ---- G4: M2 = S01 @ A2 (row-dot with A2T) ----
    if (t < 64) {
        int p0 = t & 15, k0 = t >> 4;
        float acc[4][4] = {};
        #pragma unroll
        for (int m4 = 0; m4 < 4; ++m4) {
            float4 av[4], bv[4];
            #pragma unroll
            for (int i = 0; i < 4; ++i) av[i] = ldf4(&S01[(p0+16*i)*20 + 4*m4]);
            #pragma unroll
            for (int j = 0; j < 4; ++j) bv[j] = ldf4(&A2T[(k0+4*j)*20 + 4*m4]);
            #pragma unroll
            for (int i = 0; i < 4; ++i)
                #pragma unroll
                for (int j = 0; j < 4; ++j) acc[i][j] += dot4(av[i], bv[j]);
        }
        #pragma unroll
        for (int i = 0; i < 4; ++i)
            #pragma unroll
            for (int j = 0; j < 4; ++j) M2[(p0+16*i)*20 + k0+4*j] = acc[i][j];
    }
    __syncthreads();

    // ---- G5: fusion += M2@S01^T; write A0 ----
    if (t < 128) {
        int fp0 = t & 7, fq0 = t >> 3;
        #pragma unroll
        for (int m4 = 0; m4 < 4; ++m4) {
            float4 av[8], bv[4];
            #pragma unroll
            for (int i = 0; i < 8; ++i) av[i] = ldf4(&M2[(fp0+8*i)*20 + 4*m4]);
            #pragma unroll
            for (int j = 0; j < 4; ++j) bv[j] = ldf4(&S01[(fq0+16*j)*20 + 4*m4]);
            #pragma unroll
            for (int i = 0; i < 8; ++i)
                #pragma unroll
                for (int j = 0; j < 4; ++j) facc[i][j] += dot4(av[i], bv[j]);
        }
        #pragma unroll
        for (int i = 0; i < 8; ++i)
            #pragma unroll
            for (int j = 0; j < 4; ++j) A0[(fp0+8*i)*68 + fq0+16*j] = facc[i][j];
    }
    __syncthreads();

    // ---- P13: final softmax stats ----
    if (t < 64) {
        float mx = -1e30f;
        float4 r[16];
        #pragma unroll
        for (int u = 0; u < 16; ++u) { r[u] = ldf4(&A0[t*68 + 4*u]); mx = fmaxf(mx, vmax4(r[u])); }
        float sm = 0.f;
        #pragma unroll
        for (int u = 0; u < 16; ++u) sm += vsum4(exp4(r[u], mx));
        sv[t] = mx; tv[t] = 1.f/sm;
    }
    __syncthreads();

    // ---- P14: write out ----
    for (int i = t; i < 1024; i += 512) {
        int p = i >> 4, q4 = i & 15;
        float mx = sv[p], inv = tv[p];
        float4 a = exp4(ldf4(&A0[p*68 + 4*q4]), mx);
        a.x *= inv; a.y *= inv; a.z *= inv; a.w *= inv;
        stf4(&out[(size_t)g*4096 + p*64 + 4*q4], a);
    }
}

// ================== SPATIAL: 16384 graphs of 25 nodes, 256 threads ==================
__global__ __launch_bounds__(256, 4)
void spatial_kernel(const float* __restrict__ src, const float* __restrict__ wvg,
                    const float* __restrict__ WpT0, const float* __restrict__ WpT1,
                    const float* __restrict__ b0, const float* __restrict__ b1,
                    float* __restrict__ out, int nwg8)
{
    __shared__ __align__(16) float Rx0[1700];   // x0[25][68]; then tenants
    __shared__ __align__(16) float RA0[700];    // A0/fusion [25][28]
    __shared__ __align__(16) float RPR[816];    // P0T[12][28] -> x1[12][68] -> M1[25][20] -> M2[25][12]
    __shared__ __align__(16) float RS0[500];    // S0[25][20]
    __shared__ __align__(16) float sv[32], tv[32], ua[32], va[32], rxa[8], rsa[8];

    float* x0  = Rx0;
    float* A1  = Rx0;          // [12][20]
    float* A1T = Rx0 + 240;    // [12][20]
    float* P1T = Rx0 + 480;    // [5][12]
    float* S1  = Rx0 + 540;    // [12][12]
    float* S1T = Rx0 + 684;    // [5][12]
    float* A2T = Rx0 + 744;    // [5][12]
    float* S01 = Rx0 + 804;    // [25][12]
    float* A0  = RA0;
    float* P0T = RPR;          // [12][28]
    float* x1  = RPR;          // [12][68]
    float* M1  = RPR;          // [25][20]
    float* M2  = RPR;          // [25][12]
    float* S0  = RS0;          // [25][20]

    const int t = threadIdx.x;
    const int g = (blockIdx.x & 7) * nwg8 + (blockIdx.x >> 3);
    const int b = g >> 6, inner = g & 63;
    const float* srcb = src + (size_t)b*102400 + inner*25;  // + c*1600 + r  (inner = timestep, stride 25)

    // ---- L ----
    for (int i = t; i < 400; i += 256) {
        int r = i % 25, c0 = (i / 25) << 2;
        float4 v;
        v.x = srcb[(c0+0)*1600 + r];
        v.y = srcb[(c0+1)*1600 + r];
        v.z = srcb[(c0+2)*1600 + r];
        v.w = srcb[(c0+3)*1600 + r];
        stf4(&x0[r*68 + c0], v);
    }
    __syncthreads();

    // ---- P0: dots || P0T (zero-padded cols 25..27) ----
    if (t < 50) {
        int which = t / 25, p = t - which*25;
        const float* w = wvg + which*64;
        float a = 0.f;
        #pragma unroll
        for (int c4 = 0; c4 < 16; ++c4) a += dot4(ldf4(&x0[p*68 + 4*c4]), ldf4(&w[4*c4]));
        if (which) tv[p] = a; else sv[p] = a;
    }
    for (int i = t; i < 336; i += 256) {
        int k = i / 28, m = i - k*28;
        float a = 0.f;
        if (m < 25) {
            #pragma unroll
            for (int c4 = 0; c4 < 16; ++c4) a += dot4(ldf4(&WpT0[k*64 + 4*c4]), ldf4(&x0[m*68 + 4*c4]));
        }
        P0T[k*28 + m] = a;
    }
    __syncthreads();

    // ---- P1: A0 (pads = -1e30) ----
    for (int i = t; i < 700; i += 256) {
        int p = i / 28, q = i - p*28;
        A0[i] = (q < 25) ? lrelu(sv[p] + tv[q]) : -1e30f;
    }
    __syncthreads();

    // ---- P2: S0raw ----
    for (int i = t; i < 300; i += 256) {
        int p = i / 12, k = i - p*12;
        float acc = b0[k];
        #pragma unroll
        for (int m4 = 0; m4 < 7; ++m4) acc += dot4(ldf4(&A0[p*28 + 4*m4]), ldf4(&P0T[k*28 + 4*m4]));
        S0[p*20 + k] = acc;
    }
    __syncthreads();

    // ---- P3: softmax S0 rows ----
    if (t < 25) {
        float4 r[3]; float mx = -1e30f;
        #pragma unroll
        for (int u = 0; u < 3; ++u) { r[u] = ldf4(&S0[t*20 + 4*u]); mx = fmaxf(mx, vmax4(r[u])); }
        float sm = 0.f;
        #pragma unroll
        for (int u = 0; u < 3; ++u) { r[u] = exp4(r[u], mx); sm += vsum4(r[u]); }
        float inv = 1.f/sm;
        #pragma unroll
        for (int u = 0; u < 3; ++u) {
            r[u].x *= inv; r[u].y *= inv; r[u].z *= inv; r[u].w *= inv;
            stf4(&S0[t*20 + 4*u], r[u]);
        }
    }
    __syncthreads();

    // ---- P4: x1[k][c] ----
    if (t < 96) {
        int k = t >> 3, c0 = (t & 7) << 3;
        float4 a = {0,0,0,0}, bb = {0,0,0,0};
        #pragma unroll
        for (int p = 0; p < 25; ++p) {
            float s = S0[p*20 + k];
            a  = fma4(s, ldf4(&x0[p*68 + c0]), a);
            bb = fma4(s, ldf4(&x0[p*68 + c0 + 4]), bb);
        }
        stf4(&x1[k*68 + c0], a);
        stf4(&x1[k*68 + c0 + 4], bb);
    }
    __syncthreads();

    // ---- P5: dots || P1T ----
    if (t < 48) {
        int which = t / 12, p = t - which*12;
        const float* w = wvg + (2+which)*64;
        float a = 0.f;
        #pragma unroll
        for (int c4 = 0; c4 < 16; ++c4) a += dot4(ldf4(&x1[p*68 + 4*c4]), ldf4(&w[4*c4]));
        if (which == 0) sv[p] = a; else if (which == 1) tv[p] = a;
        else if (which == 2) ua[p] = a; else va[p] = a;
    }
    for (int i = t; i < 60; i += 256) {
        int j = i / 12, k = i - j*12;
        float a = 0.f;
        #pragma unroll
        for (int c4 = 0; c4 < 16; ++c4) a += dot4(ldf4(&WpT1[j*64 + 4*c4]), ldf4(&x1[k*68 + 4*c4]));
        P1T[j*12 + k] = a;
    }
    __syncthreads();

    // ---- P6: A1, A1T ----
    for (int i = t; i < 288; i += 256) {
        int mat = i / 144, rr = (i - mat*144) / 12, q = i % 12;
        if (mat == 0) A1 [rr*20 + q] = lrelu(sv[rr] + tv[q]);
        else          A1T[rr*20 + q] = lrelu(sv[q] + tv[rr]);
    }
    __syncthreads();

    // ---- G1: M1 || S1raw ----
    for (int i = t; i < 300; i += 256) {
        int p = i / 12, k = i - p*12;
        float acc = 0.f;
        #pragma unroll
        for (int m4 = 0; m4 < 3; ++m4) acc += dot4(ldf4(&S0[p*20 + 4*m4]), ldf4(&A1T[k*20 + 4*m4]));
        M1[p*20 + k] = acc;
    }
    for (int i = t; i < 60; i += 256) {
        int m = i / 5, j = i - m*5;
        float acc = b1[j];
        #pragma unroll
        for (int k4 = 0; k4 < 3; ++k4) acc += dot4(ldf4(&A1[m*20 + 4*k4]), ldf4(&P1T[j*12 + 4*k4]));
        S1[m*12 + j] = acc;
    }
    __syncthreads();

    // ---- G2a: softmax S1 || fusion pass1 ----
    if (t < 12) {
        float mx = -1e30f;
        float r0 = S1[t*12+0], r1 = S1[t*12+1], r2 = S1[t*12+2], r3 = S1[t*12+3], r4 = S1[t*12+4];
        mx = fmaxf(fmaxf(fmaxf(r0,r1), fmaxf(r2,r3)), r4);
        r0 = __expf(r0-mx); r1 = __expf(r1-mx); r2 = __expf(r2-mx); r3 = __expf(r3-mx); r4 = __expf(r4-mx);
        float inv = 1.f/(r0+r1+r2+r3+r4);
        S1[t*12+0] = r0*inv; S1[t*12+1] = r1*inv; S1[t*12+2] = r2*inv; S1[t*12+3] = r3*inv; S1[t*12+4] = r4*inv;
    }
    for (int i = t; i < 625; i += 256) {
        int p = i / 25, q = i - p*25;
        float acc = A0[p*28 + q];
        #pragma unroll
        for (int m4 = 0; m4 < 3; ++m4) acc += dot4(ldf4(&M1[p*20 + 4*m4]), ldf4(&S0[q*20 + 4*m4]));
        A0[p*28 + q] = acc;
    }
    __syncthreads();

    // ---- G2b: S1T || rxa/rsa ----
    for (int i = t; i < 60; i += 256) {
        int j = i / 12, m = i - j*12;
        S1T[j*12 + m] = S1[m*12 + j];
    }
    if (t >= 64 && t < 74) {
        int tp = t - 64, which = tp / 5, k = tp - which*5;
        float a = 0.f;
        #pragma unroll
        for (int n = 0; n < 12; ++n) a += S1[n*12 + k] * (which ? va[n] : ua[n]);
        if (which) rsa[k] = a; else rxa[k] = a;
    }
    __syncthreads();

    // ---- G3: A2T (zero-padded) || S01 (zero-padded) ----
    for (int i = t; i < 40; i += 256) {
        int q = i >> 3, p = i & 7;
        A2T[q*12 + p] = (p < 5) ? lrelu(rxa[p] + rsa[q]) : 0.f;
    }
    for (int i = t; i < 200; i += 256) {
        int p = i >> 3, c = i & 7;
        float acc = 0.f;
        if (c < 5) {
            #pragma unroll
            for (int m4 = 0; m4 < 3; ++m4) acc += dot4(ldf4(&S0[p*20 + 4*m4]), ldf4(&S1T[c*12 + 4*m4]));
        }
        S01[p*12 + c] = acc;
    }
    __syncthreads();

    // ---- G4: M2 (zero-padded) ----
    for (int i = t; i < 200; i += 256) {
        int p = i >> 3, k = i & 7;
        float acc = 0.f;
        if (k < 5) {
            #pragma unroll
            for (int m4 = 0; m4 < 2; ++m4) acc += dot4(ldf4(&S01[p*12 + 4*m4]), ldf4(&A2T[k*12 + 4*m4]));
        }
        M2[p*12 + k] = acc;
    }
    __syncthreads();

    // ---- G5: fusion pass2 ----
    for (int i = t; i < 625; i += 256) {
        int p = i / 25, q = i - p*25;
        float acc = A0[p*28 + q];
        #pragma unroll
        for (int m4 = 0; m4 < 2; ++m4) acc += dot4(ldf4(&M2[p*12 + 4*m4]), ldf4(&S01[q*12 + 4*m4]));
        A0[p*28 + q] = acc;
    }
    __syncthreads();

    // ---- P13: stats ----
    if (t < 25) {
        float4 r[7]; float mx = -1e30f;
        #pragma unroll
        for (int u = 0; u < 7; ++u) { r[u] = ldf4(&A0[t*28 + 4*u]); mx = fmaxf(mx, vmax4(r[u])); }
        float sm = 0.f;
        #pragma unroll
        for (int u = 0; u < 7; ++u) sm += vsum4(exp4(r[u], mx));
        sv[t] = mx; tv[t] = 1.f/sm;
    }
    __syncthreads();

    // ---- P14 ----
    for (int i = t; i < 625; i += 256) {
        int p = i / 25, q = i - p*25;
        out[(size_t)g*625 + i] = __expf(A0[p*28 + q] - sv[p]) * tv[p];
    }
}

extern "C" void kernel_launch(void* const* d_in, const int* in_sizes, int n_in,
                              void* d_out, int out_size, void* d_ws, size_t ws_size,
                              hipStream_t stream) {
    const float* src = (const float*)d_in[0];
    const float* W   = (const float*)d_in[1];
    float* ws = (float*)d_ws;

    prep_kernel<<<16, 64, 0, stream>>>(W,
        (const float*)d_in[2],  (const float*)d_in[3],    // as_src0, as_dst0
        (const float*)d_in[6],  (const float*)d_in[7],    // as_src1, as_dst1
        (const float*)d_in[10], (const float*)d_in[11],   // as_src2, as_dst2
        (const float*)d_in[4],  (const float*)d_in[5],    // at_src0, at_dst0
        (const float*)d_in[8],  (const float*)d_in[9],    // at_src1, at_dst1
        (const float*)d_in[12], (const float*)d_in[13],   // at_src2, at_dst2
        (const float*)d_in[14], (const float*)d_in[16],   // Wsp0, Wsp1
        (const float*)d_in[18], (const float*)d_in[20],   // Wtp0, Wtp1
        ws);

    float* out = (float*)d_out;
    spatial_kernel<<<16384, 256, 0, stream>>>(
        src, ws, ws + 768, ws + 1536,
        (const float*)d_in[15], (const float*)d_in[17],
        out, 16384/8);
    temporal_kernel<<<6400, 512, 0, stream>>>(
        src, ws + 384, ws + 1856, ws + 3904,
        (const float*)d_in[19], (const float*)d_in[21],
        out + 10240000, 6400/8);
}

// Round 5
// 893.677 us; speedup vs baseline: 1.2823x; 1.2823x over previous
//
#include <hip/hip_runtime.h>
#include <math.h>

constexpr float LEAKY = 0.2f;

__device__ __forceinline__ float4 ldf4(const float* p){ return *reinterpret_cast<const float4*>(p); }
__device__ __forceinline__ void stf4(float* p, float4 v){ *reinterpret_cast<float4*>(p) = v; }
__device__ __forceinline__ float dot4(float4 a, float4 b){ return a.x*b.x + a.y*b.y + a.z*b.z + a.w*b.w; }
__device__ __forceinline__ float4 fma4(float s, float4 b, float4 acc){
    acc.x += s*b.x; acc.y += s*b.y; acc.z += s*b.z; acc.w += s*b.w; return acc;
}
__device__ __forceinline__ float lrelu(float f){ return f > 0.f ? f : LEAKY*f; }
__device__ __forceinline__ float4 lrelu4(float s, float4 t){
    float4 r; r.x = lrelu(s+t.x); r.y = lrelu(s+t.y); r.z = lrelu(s+t.z); r.w = lrelu(s+t.w); return r;
}
__device__ __forceinline__ float vmax4(float4 v){ return fmaxf(fmaxf(v.x,v.y), fmaxf(v.z,v.w)); }
__device__ __forceinline__ float vsum4(float4 v){ return v.x+v.y+v.z+v.w; }
__device__ __forceinline__ float4 exp4(float4 a, float mx){
    float4 r; r.x = __expf(a.x-mx); r.y = __expf(a.y-mx); r.z = __expf(a.z-mx); r.w = __expf(a.w-mx); return r;
}

// ws layout (floats): wv[12*64]@0 | WspT0[12*64]@768 | WspT1[5*64]@1536 | WtpT0[32*64]@1856 | WtpT1[16*64]@3904
__global__ void prep_kernel(const float* __restrict__ W,
    const float* a0, const float* a1, const float* a2,  const float* a3,
    const float* a4, const float* a5, const float* a6,  const float* a7,
    const float* a8, const float* a9, const float* a10, const float* a11,
    const float* __restrict__ Wsp0, const float* __restrict__ Wsp1,
    const float* __restrict__ Wtp0, const float* __restrict__ Wtp1,
    float* __restrict__ ws)
{
    int blk = blockIdx.x, t = threadIdx.x;
    if (blk < 12) {
        const float* as[12] = {a0,a1,a2,a3,a4,a5,a6,a7,a8,a9,a10,a11};
        const float* a = as[blk];
        float s = 0.f;
        #pragma unroll
        for (int h = 0; h < 128; ++h) s += W[t*128 + h] * a[h];
        ws[blk*64 + t] = s;
    } else if (blk == 12) {
        for (int i = t; i < 768; i += 64) { int k = i >> 6, c = i & 63; ws[768 + i] = Wsp0[c*12 + k]; }
    } else if (blk == 13) {
        for (int i = t; i < 320; i += 64) { int k = i >> 6, c = i & 63; ws[1536 + i] = Wsp1[c*5 + k]; }
    } else if (blk == 14) {
        for (int i = t; i < 2048; i += 64) { int k = i >> 6, c = i & 63; ws[1856 + i] = Wtp0[c*32 + k]; }
    } else {
        for (int i = t; i < 1024; i += 64) { int k = i >> 6, c = i & 63; ws[3904 + i] = Wtp1[c*16 + k]; }
    }
}

// ================== TEMPORAL: 6400 graphs of 64 nodes, 512 threads ==================
// launch_bounds(512, 2): hipcc treats 2nd arg as min BLOCKS/CU (CUDA semantics) —
// (512,4) forced VGPR<=64 and spilled the register tiles to scratch (R4: 2.3 GB traffic).
// 2 blocks/CU -> VGPR cap 128; LDS (54.8 KB) caps at 2 blocks/CU anyway.
__global__ __launch_bounds__(512, 2)
void temporal_kernel(const float* __restrict__ src, const float* __restrict__ wvg,
                     const float* __restrict__ WpT0, const float* __restrict__ WpT1,
                     const float* __restrict__ b0, const float* __restrict__ b1,
                     float* __restrict__ out, int nwg8)
{
    __shared__ __align__(16) float Rx0[4352];   // x0[64][68]; tenants after x0 dies
    __shared__ __align__(16) float RA0[4352];   // A0/fusion [64][68]
    __shared__ __align__(16) float RPR[2304];   // P0T[32][68] -> x1[32][68] -> M1[64][36] -> M2[64][20]
    __shared__ __align__(16) float RS0[2304];   // S0[64][36]
    __shared__ __align__(16) float sv[64], tv[64], ua[64], va[64], rxa[16], rsa[16];

    float* x0  = Rx0;
    float* A1  = Rx0;          // [32][36]
    float* A1T = Rx0 + 1152;   // [32][36]
    float* P1T = Rx0 + 2304;   // [16][36]
    float* S1  = Rx0 + 2880;   // [32][20]
    float* S1T = Rx0 + 3520;   // [16][36]
    float* A2T = Rx0 + 2304;   // [16][20]  (after P1T dead)
    float* S01 = Rx0;          // [64][20]  (after A1/A1T dead)
    float* A0  = RA0;
    float* P0T = RPR;          // [32][68]
    float* x1  = RPR;          // [32][68]
    float* M1  = RPR;          // [64][36]
    float* M2  = RPR;          // [64][20]
    float* S0  = RS0;          // [64][36]

    const int t = threadIdx.x;
    const int g = (blockIdx.x & 7) * nwg8 + (blockIdx.x >> 3);
    const int b = g / 25, inner = g - b*25;
    const float* srcb = src + (size_t)b*102400 + inner;  // + c*1600 + r*25  (inner = joint, stride 1)

    float facc[8][4];   // fusion accumulator (threads 0..127), lives G2a..G5

    // ---- L: load x0[r][c], stride 68 ----
    for (int i = t; i < 1024; i += 512) {
        int r = i & 63, c0 = (i >> 6) << 2;
        float4 v;
        v.x = srcb[(c0+0)*1600 + r*25];
        v.y = srcb[(c0+1)*1600 + r*25];
        v.z = srcb[(c0+2)*1600 + r*25];
        v.w = srcb[(c0+3)*1600 + r*25];
        stf4(&x0[r*68 + c0], v);
    }
    __syncthreads();

    // ---- P0: s0/t0 dots || P0T = (x0@Wp0)^T ----
    if (t < 128) {
        int which = t >> 6, p = t & 63;
        const float* w = wvg + which*64;
        float a = 0.f;
        #pragma unroll
        for (int c4 = 0; c4 < 16; ++c4) a += dot4(ldf4(&x0[p*68 + 4*c4]), ldf4(&w[4*c4]));
        if (which) tv[p] = a; else sv[p] = a;
    } else if (t < 256) {
        int tp = t - 128, k0 = tp & 7, m0 = tp >> 3;
        float acc[4][4] = {};
        #pragma unroll
        for (int c4 = 0; c4 < 16; ++c4) {
            float4 av[4], bv[4];
            #pragma unroll
            for (int i = 0; i < 4; ++i) av[i] = ldf4(&WpT0[(k0+8*i)*64 + 4*c4]);
            #pragma unroll
            for (int j = 0; j < 4; ++j) bv[j] = ldf4(&x0[(m0+16*j)*68 + 4*c4]);
            #pragma unroll
            for (int i = 0; i < 4; ++i)
                #pragma unroll
                for (int j = 0; j < 4; ++j) acc[i][j] += dot4(av[i], bv[j]);
        }
        #pragma unroll
        for (int i = 0; i < 4; ++i)
            #pragma unroll
            for (int j = 0; j < 4; ++j) P0T[(k0+8*i)*68 + m0+16*j] = acc[i][j];
    }
    __syncthreads();

    // ---- P1: A0 = lrelu(s + t^T) ----
    {
        int i = t, p = i >> 4, q4 = i & 15;
        stf4(&A0[p*68 + 4*q4], lrelu4(sv[p], ldf4(&tv[4*q4])));
        i = t + 512; p = i >> 4; q4 = i & 15;
        stf4(&A0[p*68 + 4*q4], lrelu4(sv[p], ldf4(&tv[4*q4])));
    }
    __syncthreads();

    // ---- P2: S0raw[p][k] = A0 row . P0T row + b0 ----
    if (t < 64) {
        int p0 = t & 7, k0 = t >> 3;
        float acc[8][4];
        #pragma unroll
        for (int i = 0; i < 8; ++i)
            #pragma unroll
            for (int j = 0; j < 4; ++j) acc[i][j] = b0[k0+8*j];
        #pragma unroll
        for (int m4 = 0; m4 < 16; ++m4) {
            float4 av[8], bv[4];
            #pragma unroll
            for (int i = 0; i < 8; ++i) av[i] = ldf4(&A0[(p0+8*i)*68 + 4*m4]);
            #pragma unroll
            for (int j = 0; j < 4; ++j) bv[j] = ldf4(&P0T[(k0+8*j)*68 + 4*m4]);
            #pragma unroll
            for (int i = 0; i < 8; ++i)
                #pragma unroll
                for (int j = 0; j < 4; ++j) acc[i][j] += dot4(av[i], bv[j]);
        }
        #pragma unroll
        for (int i = 0; i < 8; ++i)
            #pragma unroll
            for (int j = 0; j < 4; ++j) S0[(p0+8*i)*36 + k0+8*j] = acc[i][j];
    }
    __syncthreads();

    // ---- P3: row softmax S0 ----
    if (t < 64) {
        float4 r[8]; float mx = -1e30f;
        #pragma unroll
        for (int u = 0; u < 8; ++u) { r[u] = ldf4(&S0[t*36 + 4*u]); mx = fmaxf(mx, vmax4(r[u])); }
        float sm = 0.f;
        #pragma unroll
        for (int u = 0; u < 8; ++u) { r[u] = exp4(r[u], mx); sm += vsum4(r[u]); }
        float inv = 1.f/sm;
        #pragma unroll
        for (int u = 0; u < 8; ++u) {
            r[u].x *= inv; r[u].y *= inv; r[u].z *= inv; r[u].w *= inv;
            stf4(&S0[t*36 + 4*u], r[u]);
        }
    }
    __syncthreads();

    // ---- P4: x1[k][c] = sum_p S0[p][k] * x0[p][c]  (4k x 8c tiles) ----
    if (t < 64) {
        int k0 = (t & 7) << 2, c0 = (t >> 3) << 3;
        float4 accA[4] = {}, accB[4] = {};
        #pragma unroll 8
        for (int p = 0; p < 64; ++p) {
            float4 s4 = ldf4(&S0[p*36 + k0]);
            float4 xa = ldf4(&x0[p*68 + c0]);
            float4 xb = ldf4(&x0[p*68 + c0 + 4]);
            accA[0] = fma4(s4.x, xa, accA[0]); accB[0] = fma4(s4.x, xb, accB[0]);
            accA[1] = fma4(s4.y, xa, accA[1]); accB[1] = fma4(s4.y, xb, accB[1]);
            accA[2] = fma4(s4.z, xa, accA[2]); accB[2] = fma4(s4.z, xb, accB[2]);
            accA[3] = fma4(s4.w, xa, accA[3]); accB[3] = fma4(s4.w, xb, accB[3]);
        }
        #pragma unroll
        for (int ki = 0; ki < 4; ++ki) {
            stf4(&x1[(k0+ki)*68 + c0], accA[ki]);
            stf4(&x1[(k0+ki)*68 + c0 + 4], accB[ki]);
        }
    }
    __syncthreads();

    // ---- P5: s1/t1/u/v dots || P1T = (x1@Wp1)^T ----
    if (t < 128) {
        int which = t >> 5, p = t & 31;
        const float* w = wvg + (2+which)*64;
        float a = 0.f;
        #pragma unroll
        for (int c4 = 0; c4 < 16; ++c4) a += dot4(ldf4(&x1[p*68 + 4*c4]), ldf4(&w[4*c4]));
        if (which == 0) sv[p] = a; else if (which == 1) tv[p] = a;
        else if (which == 2) ua[p] = a; else va[p] = a;
    } else if (t < 256) {
        int tp = t - 128, j = tp >> 3, k0 = tp & 7;
        float acc[4] = {};
        #pragma unroll
        for (int c4 = 0; c4 < 16; ++c4) {
            float4 wv4 = ldf4(&WpT1[j*64 + 4*c4]);
            #pragma unroll
            for (int i = 0; i < 4; ++i) acc[i] += dot4(ldf4(&x1[(k0+8*i)*68 + 4*c4]), wv4);
        }
        #pragma unroll
        for (int i = 0; i < 4; ++i) P1T[j*36 + k0+8*i] = acc[i];
    }
    __syncthreads();

    // ---- P6: A1, A1T ----
    {
        int mat = t >> 8, p = (t >> 3) & 31, q4 = t & 7;
        if (mat == 0) stf4(&A1 [p*36 + 4*q4], lrelu4(sv[p], ldf4(&tv[4*q4])));
        else          stf4(&A1T[p*36 + 4*q4], lrelu4(tv[p], ldf4(&sv[4*q4])));
    }
    __syncthreads();

    // ---- G1: M1 = S0 @ A1 (row-dot with A1T) || S1raw = A1@P1 + b1 ----
    if (t < 64) {
        int p0 = t & 7, k0 = t >> 3;
        float acc[8][4] = {};
        #pragma unroll
        for (int m4 = 0; m4 < 8; ++m4) {
            float4 av[8], bv[4];
            #pragma unroll
            for (int i = 0; i < 8; ++i) av[i] = ldf4(&S0[(p0+8*i)*36 + 4*m4]);
            #pragma unroll
            for (int j = 0; j < 4; ++j) bv[j] = ldf4(&A1T[(k0+8*j)*36 + 4*m4]);
            #pragma unroll
            for (int i = 0; i < 8; ++i)
                #pragma unroll
                for (int j = 0; j < 4; ++j) acc[i][j] += dot4(av[i], bv[j]);
        }
        #pragma unroll
        for (int i = 0; i < 8; ++i)
            #pragma unroll
            for (int j = 0; j < 4; ++j) M1[(p0+8*i)*36 + k0+8*j] = acc[i][j];
    } else if (t < 96) {
        int tp = t - 64, m0 = tp & 7, j0 = tp >> 3;
        float acc[4][4];
        #pragma unroll
        for (int i = 0; i < 4; ++i)
            #pragma unroll
            for (int j = 0; j < 4; ++j) acc[i][j] = b1[j0+4*j];
        #pragma unroll
        for (int k4 = 0; k4 < 8; ++k4) {
            float4 av[4], bv[4];
            #pragma unroll
            for (int i = 0; i < 4; ++i) av[i] = ldf4(&A1[(m0+8*i)*36 + 4*k4]);
            #pragma unroll
            for (int j = 0; j < 4; ++j) bv[j] = ldf4(&P1T[(j0+4*j)*36 + 4*k4]);
            #pragma unroll
            for (int i = 0; i < 4; ++i)
                #pragma unroll
                for (int j = 0; j < 4; ++j) acc[i][j] += dot4(av[i], bv[j]);
        }
        #pragma unroll
        for (int i = 0; i < 4; ++i)
            #pragma unroll
            for (int j = 0; j < 4; ++j) S1[(m0+8*i)*20 + j0+4*j] = acc[i][j];
    }
    __syncthreads();

    // ---- G2a: fusion regs = A0 + M1@S0^T || softmax S1 ----
    {
        int fp0 = t & 7, fq0 = t >> 3;
        if (t < 128) {
            #pragma unroll
            for (int i = 0; i < 8; ++i)
                #pragma unroll
                for (int j = 0; j < 4; ++j) facc[i][j] = A0[(fp0+8*i)*68 + fq0+16*j];
            #pragma unroll
            for (int m4 = 0; m4 < 8; ++m4) {
                float4 av[8], bv[4];
                #pragma unroll
                for (int i = 0; i < 8; ++i) av[i] = ldf4(&M1[(fp0+8*i)*36 + 4*m4]);
                #pragma unroll
                for (int j = 0; j < 4; ++j) bv[j] = ldf4(&S0[(fq0+16*j)*36 + 4*m4]);
                #pragma unroll
                for (int i = 0; i < 8; ++i)
                    #pragma unroll
                    for (int j = 0; j < 4; ++j) facc[i][j] += dot4(av[i], bv[j]);
            }
        } else if (t < 160) {
            int m = t - 128;
            float4 r[4]; float mx = -1e30f;
            #pragma unroll
            for (int u = 0; u < 4; ++u) { r[u] = ldf4(&S1[m*20 + 4*u]); mx = fmaxf(mx, vmax4(r[u])); }
            float sm = 0.f;
            #pragma unroll
            for (int u = 0; u < 4; ++u) { r[u] = exp4(r[u], mx); sm += vsum4(r[u]); }
            float inv = 1.f/sm;
            #pragma unroll
            for (int u = 0; u < 4; ++u) {
                r[u].x *= inv; r[u].y *= inv; r[u].z *= inv; r[u].w *= inv;
                stf4(&S1[m*20 + 4*u], r[u]);
            }
        }
    }
    __syncthreads();

    // ---- G2b: S1T || rxa/rsa = S1^T . (u,v) ----
    if (t < 256) {
        for (int i = t; i < 512; i += 256) { int j = i >> 5, m = i & 31; S1T[j*36 + m] = S1[m*20 + j]; }
    } else if (t >= 448 && t < 480) {
        int tp = t - 448, k = tp & 15, which = tp >> 4;
        float a = 0.f;
        #pragma unroll
        for (int n = 0; n < 32; ++n) a += S1[n*20 + k] * (which ? va[n] : ua[n]);
        if (which) rsa[k] = a; else rxa[k] = a;
    }
    __syncthreads();

    // ---- G3: S01 = S0 @ S1 (row-dot with S1T) || A2T build ----
    if (t < 64) {
        int p0 = t & 15, j0 = t >> 4;
        float acc[4][4] = {};
        #pragma unroll
        for (int m4 = 0; m4 < 8; ++m4) {
            float4 av[4], bv[4];
            #pragma unroll
            for (int i = 0; i < 4; ++i) av[i] = ldf4(&S0[(p0+16*i)*36 + 4*m4]);
            #pragma unroll
            for (int j = 0; j < 4; ++j) bv[j] = ldf4(&S1T[(j0+4*j)*36 + 4*m4]);
            #pragma unroll
            for (int i = 0; i < 4; ++i)
                #pragma unroll
                for (int j = 0; j < 4; ++j) acc[i][j] += dot4(av[i], bv[j]);
        }
        #pragma unroll
        for (int i = 0; i < 4; ++i)
            #pragma unroll
            for (int j = 0; j < 4; ++j) S01[(p0+16*i)*20 + j0+4*j] = acc[i][j];
    } else if (t >= 256) {
        int i = t - 256, q = i >> 4, p = i & 15;
        A2T[q*20 + p] = lrelu(rxa[p] + rsa[q]);
    }
    __syncthreads();

    // ---- G4: M2 = S01 @ A2 (row-dot with A2T) ----
    if (t < 64) {
        int p0 = t & 15, k0 = t >> 4;
        float acc[4][4] = {};
        #pragma unroll
        for (int m4 = 0; m4 < 4; ++m4) {
            float4 av[4], bv[4];
            #pragma unroll
            for (int i = 0; i < 4; ++i) av[i] = ldf4(&S01[(p0+16*i)*20 + 4*m4]);
            #pragma unroll
            for (int j = 0; j < 4; ++j) bv[j] = ldf4(&A2T[(k0+4*j)*20 + 4*m4]);
            #pragma unroll
            for (int i = 0; i < 4; ++i)
                #pragma unroll
                for (int j = 0; j < 4; ++j) acc[i][j] += dot4(av[i], bv[j]);
        }
        #pragma unroll
        for (int i = 0; i < 4; ++i)
            #pragma unroll
            for (int j = 0; j < 4; ++j) M2[(p0+16*i)*20 + k0+4*j] = acc[i][j];
    }
    __syncthreads();

    // ---- G5: fusion += M2@S01^T; write A0 ----
    if (t < 128) {
        int fp0 = t & 7, fq0 = t >> 3;
        #pragma unroll
        for (int m4 = 0; m4 < 4; ++m4) {
            float4 av[8], bv[4];
            #pragma unroll
            for (int i = 0; i < 8; ++i) av[i] = ldf4(&M2[(fp0+8*i)*20 + 4*m4]);
            #pragma unroll
            for (int j = 0; j < 4; ++j) bv[j] = ldf4(&S01[(fq0+16*j)*20 + 4*m4]);
            #pragma unroll
            for (int i = 0; i < 8; ++i)
                #pragma unroll
                for (int j = 0; j < 4; ++j) facc[i][j] += dot4(av[i], bv[j]);
        }
        #pragma unroll
        for (int i = 0; i < 8; ++i)
            #pragma unroll
            for (int j = 0; j < 4; ++j) A0[(fp0+8*i)*68 + fq0+16*j] = facc[i][j];
    }
    __syncthreads();

    // ---- P13: final softmax stats ----
    if (t < 64) {
        float mx = -1e30f;
        float4 r[16];
        #pragma unroll
        for (int u = 0; u < 16; ++u) { r[u] = ldf4(&A0[t*68 + 4*u]); mx = fmaxf(mx, vmax4(r[u])); }
        float sm = 0.f;
        #pragma unroll
        for (int u = 0; u < 16; ++u) sm += vsum4(exp4(r[u], mx));
        sv[t] = mx; tv[t] = 1.f/sm;
    }
    __syncthreads();

    // ---- P14: write out ----
    for (int i = t; i < 1024; i += 512) {
        int p = i >> 4, q4 = i & 15;
        float mx = sv[p], inv = tv[p];
        float4 a = exp4(ldf4(&A0[p*68 + 4*q4]), mx);
        a.x *= inv; a.y *= inv; a.z *= inv; a.w *= inv;
        stf4(&out[(size_t)g*4096 + p*64 + 4*q4], a);
    }
}

// ================== SPATIAL: 16384 graphs of 25 nodes, 256 threads ==================
__global__ __launch_bounds__(256, 4)
void spatial_kernel(const float* __restrict__ src, const float* __restrict__ wvg,
                    const float* __restrict__ WpT0, const float* __restrict__ WpT1,
                    const float* __restrict__ b0, const float* __restrict__ b1,
                    float* __restrict__ out, int nwg8)
{
    __shared__ __align__(16) float Rx0[1700];   // x0[25][68]; then tenants
    __shared__ __align__(16) float RA0[700];    // A0/fusion [25][28]
    __shared__ __align__(16) float RPR[816];    // P0T[12][28] -> x1[12][68] -> M1[25][20] -> M2[25][12]
    __shared__ __align__(16) float RS0[500];    // S0[25][20]
    __shared__ __align__(16) float sv[32], tv[32], ua[32], va[32], rxa[8], rsa[8];

    float* x0  = Rx0;
    float* A1  = Rx0;          // [12][20]
    float* A1T = Rx0 + 240;    // [12][20]
    float* P1T = Rx0 + 480;    // [5][12]
    float* S1  = Rx0 + 540;    // [12][12]
    float* S1T = Rx0 + 684;    // [5][12]
    float* A2T = Rx0 + 744;    // [5][12]
    float* S01 = Rx0 + 804;    // [25][12]
    float* A0  = RA0;
    float* P0T = RPR;          // [12][28]
    float* x1  = RPR;          // [12][68]
    float* M1  = RPR;          // [25][20]
    float* M2  = RPR;          // [25][12]
    float* S0  = RS0;          // [25][20]

    const int t = threadIdx.x;
    const int g = (blockIdx.x & 7) * nwg8 + (blockIdx.x >> 3);
    const int b = g >> 6, inner = g & 63;
    const float* srcb = src + (size_t)b*102400 + inner*25;  // + c*1600 + r  (inner = timestep, stride 25)

    // ---- L ----
    for (int i = t; i < 400; i += 256) {
        int r = i % 25, c0 = (i / 25) << 2;
        float4 v;
        v.x = srcb[(c0+0)*1600 + r];
        v.y = srcb[(c0+1)*1600 + r];
        v.z = srcb[(c0+2)*1600 + r];
        v.w = srcb[(c0+3)*1600 + r];
        stf4(&x0[r*68 + c0], v);
    }
    __syncthreads();

    // ---- P0: dots || P0T (zero-padded cols 25..27) ----
    if (t < 50) {
        int which = t / 25, p = t - which*25;
        const float* w = wvg + which*64;
        float a = 0.f;
        #pragma unroll
        for (int c4 = 0; c4 < 16; ++c4) a += dot4(ldf4(&x0[p*68 + 4*c4]), ldf4(&w[4*c4]));
        if (which) tv[p] = a; else sv[p] = a;
    }
    for (int i = t; i < 336; i += 256) {
        int k = i / 28, m = i - k*28;
        float a = 0.f;
        if (m < 25) {
            #pragma unroll
            for (int c4 = 0; c4 < 16; ++c4) a += dot4(ldf4(&WpT0[k*64 + 4*c4]), ldf4(&x0[m*68 + 4*c4]));
        }
        P0T[k*28 + m] = a;
    }
    __syncthreads();

    // ---- P1: A0 (pads = -1e30) ----
    for (int i = t; i < 700; i += 256) {
        int p = i / 28, q = i - p*28;
        A0[i] = (q < 25) ? lrelu(sv[p] + tv[q]) : -1e30f;
    }
    __syncthreads();

    // ---- P2: S0raw ----
    for (int i = t; i < 300; i += 256) {
        int p = i / 12, k = i - p*12;
        float acc = b0[k];
        #pragma unroll
        for (int m4 = 0; m4 < 7; ++m4) acc += dot4(ldf4(&A0[p*28 + 4*m4]), ldf4(&P0T[k*28 + 4*m4]));
        S0[p*20 + k] = acc;
    }
    __syncthreads();

    // ---- P3: softmax S0 rows ----
    if (t < 25) {
        float4 r[3]; float mx = -1e30f;
        #pragma unroll
        for (int u = 0; u < 3; ++u) { r[u] = ldf4(&S0[t*20 + 4*u]); mx = fmaxf(mx, vmax4(r[u])); }
        float sm = 0.f;
        #pragma unroll
        for (int u = 0; u < 3; ++u) { r[u] = exp4(r[u], mx); sm += vsum4(r[u]); }
        float inv = 1.f/sm;
        #pragma unroll
        for (int u = 0; u < 3; ++u) {
            r[u].x *= inv; r[u].y *= inv; r[u].z *= inv; r[u].w *= inv;
            stf4(&S0[t*20 + 4*u], r[u]);
        }
    }
    __syncthreads();

    // ---- P4: x1[k][c] ----
    if (t < 96) {
        int k = t >> 3, c0 = (t & 7) << 3;
        float4 a = {0,0,0,0}, bb = {0,0,0,0};
        #pragma unroll
        for (int p = 0; p < 25; ++p) {
            float s = S0[p*20 + k];
            a  = fma4(s, ldf4(&x0[p*68 + c0]), a);
            bb = fma4(s, ldf4(&x0[p*68 + c0 + 4]), bb);
        }
        stf4(&x1[k*68 + c0], a);
        stf4(&x1[k*68 + c0 + 4], bb);
    }
    __syncthreads();

    // ---- P5: dots || P1T ----
    if (t < 48) {
        int which = t / 12, p = t - which*12;
        const float* w = wvg + (2+which)*64;
        float a = 0.f;
        #pragma unroll
        for (int c4 = 0; c4 < 16; ++c4) a += dot4(ldf4(&x1[p*68 + 4*c4]), ldf4(&w[4*c4]));
        if (which == 0) sv[p] = a; else if (which == 1) tv[p] = a;
        else if (which == 2) ua[p] = a; else va[p] = a;
    }
    for (int i = t; i < 60; i += 256) {
        int j = i / 12, k = i - j*12;
        float a = 0.f;
        #pragma unroll
        for (int c4 = 0; c4 < 16; ++c4) a += dot4(ldf4(&WpT1[j*64 + 4*c4]), ldf4(&x1[k*68 + 4*c4]));
        P1T[j*12 + k] = a;
    }
    __syncthreads();

    // ---- P6: A1, A1T ----
    for (int i = t; i < 288; i += 256) {
        int mat = i / 144, rr = (i - mat*144) / 12, q = i % 12;
        if (mat == 0) A1 [rr*20 + q] = lrelu(sv[rr] + tv[q]);
        else          A1T[rr*20 + q] = lrelu(sv[q] + tv[rr]);
    }
    __syncthreads();

    // ---- G1: M1 || S1raw ----
    for (int i = t; i < 300; i += 256) {
        int p = i / 12, k = i - p*12;
        float acc = 0.f;
        #pragma unroll
        for (int m4 = 0; m4 < 3; ++m4) acc += dot4(ldf4(&S0[p*20 + 4*m4]), ldf4(&A1T[k*20 + 4*m4]));
        M1[p*20 + k] = acc;
    }
    for (int i = t; i < 60; i += 256) {
        int m = i / 5, j = i - m*5;
        float acc = b1[j];
        #pragma unroll
        for (int k4 = 0; k4 < 3; ++k4) acc += dot4(ldf4(&A1[m*20 + 4*k4]), ldf4(&P1T[j*12 + 4*k4]));
        S1[m*12 + j] = acc;
    }
    __syncthreads();

    // ---- G2a: softmax S1 || fusion pass1 ----
    if (t < 12) {
        float mx = -1e30f;
        float r0 = S1[t*12+0], r1 = S1[t*12+1], r2 = S1[t*12+2], r3 = S1[t*12+3], r4 = S1[t*12+4];
        mx = fmaxf(fmaxf(fmaxf(r0,r1), fmaxf(r2,r3)), r4);
        r0 = __expf(r0-mx); r1 = __expf(r1-mx); r2 = __expf(r2-mx); r3 = __expf(r3-mx); r4 = __expf(r4-mx);
        float inv = 1.f/(r0+r1+r2+r3+r4);
        S1[t*12+0] = r0*inv; S1[t*12+1] = r1*inv; S1[t*12+2] = r2*inv; S1[t*12+3] = r3*inv; S1[t*12+4] = r4*inv;
    }
    for (int i = t; i < 625; i += 256) {
        int p = i / 25, q = i - p*25;
        float acc = A0[p*28 + q];
        #pragma unroll
        for (int m4 = 0; m4 < 3; ++m4) acc += dot4(ldf4(&M1[p*20 + 4*m4]), ldf4(&S0[q*20 + 4*m4]));
        A0[p*28 + q] = acc;
    }
    __syncthreads();

    // ---- G2b: S1T || rxa/rsa ----
    for (int i = t; i < 60; i += 256) {
        int j = i / 12, m = i - j*12;
        S1T[j*12 + m] = S1[m*12 + j];
    }
    if (t >= 64 && t < 74) {
        int tp = t - 64, which = tp / 5, k = tp - which*5;
        float a = 0.f;
        #pragma unroll
        for (int n = 0; n < 12; ++n) a += S1[n*12 + k] * (which ? va[n] : ua[n]);
        if (which) rsa[k] = a; else rxa[k] = a;
    }
    __syncthreads();

    // ---- G3: A2T (zero-padded) || S01 (zero-padded) ----
    for (int i = t; i < 40; i += 256) {
        int q = i >> 3, p = i & 7;
        A2T[q*12 + p] = (p < 5) ? lrelu(rxa[p] + rsa[q]) : 0.f;
    }
    for (int i = t; i < 200; i += 256) {
        int p = i >> 3, c = i & 7;
        float acc = 0.f;
        if (c < 5) {
            #pragma unroll
            for (int m4 = 0; m4 < 3; ++m4) acc += dot4(ldf4(&S0[p*20 + 4*m4]), ldf4(&S1T[c*12 + 4*m4]));
        }
        S01[p*12 + c] = acc;
    }
    __syncthreads();

    // ---- G4: M2 (zero-padded) ----
    for (int i = t; i < 200; i += 256) {
        int p = i >> 3, k = i & 7;
        float acc = 0.f;
        if (k < 5) {
            #pragma unroll
            for (int m4 = 0; m4 < 2; ++m4) acc += dot4(ldf4(&S01[p*12 + 4*m4]), ldf4(&A2T[k*12 + 4*m4]));
        }
        M2[p*12 + k] = acc;
    }
    __syncthreads();

    // ---- G5: fusion pass2 ----
    for (int i = t; i < 625; i += 256) {
        int p = i / 25, q = i - p*25;
        float acc = A0[p*28 + q];
        #pragma unroll
        for (int m4 = 0; m4 < 2; ++m4) acc += dot4(ldf4(&M2[p*12 + 4*m4]), ldf4(&S01[q*12 + 4*m4]));
        A0[p*28 + q] = acc;
    }
    __syncthreads();

    // ---- P13: stats ----
    if (t < 25) {
        float4 r[7]; float mx = -1e30f;
        #pragma unroll
        for (int u = 0; u < 7; ++u) { r[u] = ldf4(&A0[t*28 + 4*u]); mx = fmaxf(mx, vmax4(r[u])); }
        float sm = 0.f;
        #pragma unroll
        for (int u = 0; u < 7; ++u) sm += vsum4(exp4(r[u], mx));
        sv[t] = mx; tv[t] = 1.f/sm;
    }
    __syncthreads();

    // ---- P14 ----
    for (int i = t; i < 625; i += 256) {
        int p = i / 25, q = i - p*25;
        out[(size_t)g*625 + i] = __expf(A0[p*28 + q] - sv[p]) * tv[p];
    }
}

extern "C" void kernel_launch(void* const* d_in, const int* in_sizes, int n_in,
                              void* d_out, int out_size, void* d_ws, size_t ws_size,
                              hipStream_t stream) {
    const float* src = (const float*)d_in[0];
    const float* W   = (const float*)d_in[1];
    float* ws = (float*)d_ws;

    prep_kernel<<<16, 64, 0, stream>>>(W,
        (const float*)d_in[2],  (const float*)d_in[3],    // as_src0, as_dst0
        (const float*)d_in[6],  (const float*)d_in[7],    // as_src1, as_dst1
        (const float*)d_in[10], (const float*)d_in[11],   // as_src2, as_dst2
        (const float*)d_in[4],  (const float*)d_in[5],    // at_src0, at_dst0
        (const float*)d_in[8],  (const float*)d_in[9],    // at_src1, at_dst1
        (const float*)d_in[12], (const float*)d_in[13],   // at_src2, at_dst2
        (const float*)d_in[14], (const float*)d_in[16],   // Wsp0, Wsp1
        (const float*)d_in[18], (const float*)d_in[20],   // Wtp0, Wtp1
        ws);

    float* out = (float*)d_out;
    spatial_kernel<<<16384, 256, 0, stream>>>(
        src, ws, ws + 768, ws + 1536,
        (const float*)d_in[15], (const float*)d_in[17],
        out, 16384/8);
    temporal_kernel<<<6400, 512, 0, stream>>>(
        src, ws + 384, ws + 1856, ws + 3904,
        (const float*)d_in[19], (const float*)d_in[21],
        out + 10240000, 6400/8);
}

// Round 6
// 569.536 us; speedup vs baseline: 2.0121x; 1.5691x over previous
//
#include <hip/hip_runtime.h>
#include <math.h>

constexpr float LEAKY = 0.2f;

__device__ __forceinline__ float4 ldf4(const float* p){ return *reinterpret_cast<const float4*>(p); }
__device__ __forceinline__ void stf4(float* p, float4 v){ *reinterpret_cast<float4*>(p) = v; }
__device__ __forceinline__ float dot4(float4 a, float4 b){ return a.x*b.x + a.y*b.y + a.z*b.z + a.w*b.w; }
__device__ __forceinline__ float4 fma4(float s, float4 b, float4 acc){
    acc.x += s*b.x; acc.y += s*b.y; acc.z += s*b.z; acc.w += s*b.w; return acc;
}
__device__ __forceinline__ float lrelu(float f){ return f > 0.f ? f : LEAKY*f; }
__device__ __forceinline__ float4 lrelu4(float s, float4 t){
    float4 r; r.x = lrelu(s+t.x); r.y = lrelu(s+t.y); r.z = lrelu(s+t.z); r.w = lrelu(s+t.w); return r;
}
__device__ __forceinline__ float vmax4(float4 v){ return fmaxf(fmaxf(v.x,v.y), fmaxf(v.z,v.w)); }
__device__ __forceinline__ float vsum4(float4 v){ return v.x+v.y+v.z+v.w; }
__device__ __forceinline__ float4 exp4(float4 a, float mx){
    float4 r; r.x = __expf(a.x-mx); r.y = __expf(a.y-mx); r.z = __expf(a.z-mx); r.w = __expf(a.w-mx); return r;
}

// ws layout (floats): wv[12*64]@0 | WspT0[12*64]@768 | WspT1[5*64]@1536 | WtpT0[32*64]@1856 | WtpT1[16*64]@3904
__global__ void prep_kernel(const float* __restrict__ W,
    const float* a0, const float* a1, const float* a2,  const float* a3,
    const float* a4, const float* a5, const float* a6,  const float* a7,
    const float* a8, const float* a9, const float* a10, const float* a11,
    const float* __restrict__ Wsp0, const float* __restrict__ Wsp1,
    const float* __restrict__ Wtp0, const float* __restrict__ Wtp1,
    float* __restrict__ ws)
{
    int blk = blockIdx.x, t = threadIdx.x;
    if (blk < 12) {
        const float* as[12] = {a0,a1,a2,a3,a4,a5,a6,a7,a8,a9,a10,a11};
        const float* a = as[blk];
        float s = 0.f;
        #pragma unroll
        for (int h = 0; h < 128; ++h) s += W[t*128 + h] * a[h];
        ws[blk*64 + t] = s;
    } else if (blk == 12) {
        for (int i = t; i < 768; i += 64) { int k = i >> 6, c = i & 63; ws[768 + i] = Wsp0[c*12 + k]; }
    } else if (blk == 13) {
        for (int i = t; i < 320; i += 64) { int k = i >> 6, c = i & 63; ws[1536 + i] = Wsp1[c*5 + k]; }
    } else if (blk == 14) {
        for (int i = t; i < 2048; i += 64) { int k = i >> 6, c = i & 63; ws[1856 + i] = Wtp0[c*32 + k]; }
    } else {
        for (int i = t; i < 1024; i += 64) { int k = i >> 6, c = i & 63; ws[3904 + i] = Wtp1[c*16 + k]; }
    }
}

// ================== TEMPORAL: 6400 graphs of 64 nodes, 512 threads ==================
// (512,2): min 2 blocks/CU -> VGPR cap 128 (R4: (512,4) capped 64 -> scratch spills).
// All phases full-width: B-operand rows lane-fast (stride-1, row strides = 4 mod 32),
// A-operand rows broadcast per 16-lane group; shfl reductions for dots/softmax.
__global__ __launch_bounds__(512, 2)
void temporal_kernel(const float* __restrict__ src, const float* __restrict__ wvg,
                     const float* __restrict__ WpT0, const float* __restrict__ WpT1,
                     const float* __restrict__ b0, const float* __restrict__ b1,
                     float* __restrict__ out, int nwg8)
{
    __shared__ __align__(16) float Rx0[4352];   // x0[64][68]; tenants after deps clear
    __shared__ __align__(16) float RA0[4352];   // A0/fusion [64][68]
    __shared__ __align__(16) float RPR[2304];   // P0T[32][68] -> x1[32][68] -> M1[64][36] -> M2[64][20]
    __shared__ __align__(16) float RS0[2304];   // S0[64][36]
    __shared__ __align__(16) float sv[64], tv[64], ua[64], va[64], rxa[16], rsa[16];

    float* x0  = Rx0;
    float* A1  = Rx0;          // [32][36] @0      (written P6, dead after G1b)
    float* A1T = Rx0 + 1152;   // [32][36]         (written P6, dead after G1)
    float* P1T = Rx0 + 2304;   // [16][36]         (written P6, dead after G1b)
    float* S1  = Rx0 + 2880;   // [32][20]         (written G1b, dead after G2b)
    float* S1T = Rx0 + 3520;   // [16][36]         (written G2b)
    float* A2T = Rx0 + 2304;   // [16][20]         (written G4, after P1T dead)
    float* S01 = Rx0;          // [64][20]         (written G3, after A1/A1T dead)
    float* A0  = RA0;
    float* P0T = RPR;          // [32][68]
    float* x1  = RPR;          // [32][68] (P0T dead after P2)
    float* M1  = RPR;          // [64][36] (x1 dead after P6)
    float* M2  = RPR;          // [64][20] (M1 dead after G2)
    float* S0  = RS0;          // [64][36]

    const int t = threadIdx.x;
    const int g = (blockIdx.x & 7) * nwg8 + (blockIdx.x >> 3);
    const int b = g / 25, inner = g - b*25;
    const float* srcb = src + (size_t)b*102400 + inner;  // + c*1600 + r*25 (inner = joint, stride 1)

    float facc[2][4];   // fusion accumulator, ALL 512 threads, lives G2..G6

    // ---- L: load x0[r][c] ----
    for (int i = t; i < 1024; i += 512) {
        int r = i & 63, c0 = (i >> 6) << 2;
        float4 v;
        v.x = srcb[(c0+0)*1600 + r*25];
        v.y = srcb[(c0+1)*1600 + r*25];
        v.z = srcb[(c0+2)*1600 + r*25];
        v.w = srcb[(c0+3)*1600 + r*25];
        stf4(&x0[r*68 + c0], v);
    }
    __syncthreads();

    // ---- D: s0/t0 dots, 2x64x4 lanes, shfl4 reduce ----
    {
        int which = t >> 8, p = (t >> 2) & 63, l4 = t & 3;
        const float* w = wvg + which*64 + l4*16;
        const float* xr = &x0[p*68 + l4*16];
        float a = 0.f;
        #pragma unroll
        for (int c4 = 0; c4 < 4; ++c4) a += dot4(ldf4(&xr[4*c4]), ldf4(&w[4*c4]));
        a += __shfl_xor(a, 1); a += __shfl_xor(a, 2);
        if (l4 == 0) { if (which) tv[p] = a; else sv[p] = a; }
    }
    __syncthreads();

    // ---- P0T: (x0@Wp0)^T, 1k x 4m tiles (m lane-fast) ----
    {
        int m0 = t & 15, k = t >> 4;
        float acc[4] = {};
        #pragma unroll
        for (int c4 = 0; c4 < 16; ++c4) {
            float4 w4 = ldf4(&WpT0[k*64 + 4*c4]);
            #pragma unroll
            for (int jm = 0; jm < 4; ++jm)
                acc[jm] += dot4(ldf4(&x0[(m0+16*jm)*68 + 4*c4]), w4);
        }
        #pragma unroll
        for (int jm = 0; jm < 4; ++jm) P0T[k*68 + m0+16*jm] = acc[jm];
    }
    __syncthreads();

    // ---- P1: A0 = lrelu(s + t^T) ----
    for (int i = t; i < 1024; i += 512) {
        int p = i >> 4, q4 = i & 15;
        stf4(&A0[p*68 + 4*q4], lrelu4(sv[p], ldf4(&tv[4*q4])));
    }
    __syncthreads();

    // ---- P2: S0raw, 2p x 2k tiles (k lane-fast, p broadcast) ----
    {
        int k0 = t & 15, p0 = t >> 4;
        float acc[2][2];
        acc[0][0] = acc[1][0] = b0[k0];
        acc[0][1] = acc[1][1] = b0[k0+16];
        #pragma unroll
        for (int m4 = 0; m4 < 16; ++m4) {
            float4 a0 = ldf4(&A0[p0*68 + 4*m4]);
            float4 a1 = ldf4(&A0[(p0+32)*68 + 4*m4]);
            float4 pk0 = ldf4(&P0T[k0*68 + 4*m4]);
            float4 pk1 = ldf4(&P0T[(k0+16)*68 + 4*m4]);
            acc[0][0] += dot4(a0,pk0); acc[0][1] += dot4(a0,pk1);
            acc[1][0] += dot4(a1,pk0); acc[1][1] += dot4(a1,pk1);
        }
        #pragma unroll
        for (int i = 0; i < 2; ++i)
            #pragma unroll
            for (int j = 0; j < 2; ++j) S0[(p0+32*i)*36 + k0+16*j] = acc[i][j];
    }
    __syncthreads();

    // ---- P3: softmax S0 rows, 8 lanes/row ----
    {
        int p = t >> 3, l = t & 7;
        float4 v = ldf4(&S0[p*36 + 4*l]);
        float mx = vmax4(v);
        mx = fmaxf(mx, __shfl_xor(mx,1)); mx = fmaxf(mx, __shfl_xor(mx,2)); mx = fmaxf(mx, __shfl_xor(mx,4));
        v = exp4(v, mx);
        float sm = vsum4(v);
        sm += __shfl_xor(sm,1); sm += __shfl_xor(sm,2); sm += __shfl_xor(sm,4);
        float inv = 1.f/sm;
        v.x *= inv; v.y *= inv; v.z *= inv; v.w *= inv;
        stf4(&S0[p*36 + 4*l], v);
    }
    __syncthreads();

    // ---- P4: x1[k][c] outer-product (c4 lane-fast, k broadcast) ----
    {
        int c4 = t & 15, k = t >> 4;
        float4 acc = {0,0,0,0};
        #pragma unroll 8
        for (int p = 0; p < 64; ++p)
            acc = fma4(S0[p*36 + k], ldf4(&x0[p*68 + 4*c4]), acc);
        stf4(&x1[k*68 + 4*c4], acc);
    }
    __syncthreads();

    // ---- P5: s1/t1/u/v dots, 4x32x4 lanes ----
    {
        int which = t >> 7, p = (t >> 2) & 31, l4 = t & 3;
        const float* w = wvg + (2+which)*64 + l4*16;
        const float* xr = &x1[p*68 + l4*16];
        float a = 0.f;
        #pragma unroll
        for (int c4 = 0; c4 < 4; ++c4) a += dot4(ldf4(&xr[4*c4]), ldf4(&w[4*c4]));
        a += __shfl_xor(a, 1); a += __shfl_xor(a, 2);
        if (l4 == 0) {
            if (which == 0) sv[p] = a; else if (which == 1) tv[p] = a;
            else if (which == 2) ua[p] = a; else va[p] = a;
        }
    }
    __syncthreads();

    // ---- P6: A1+A1T (t<256) || P1T (t>=256) ----
    if (t < 256) {
        for (int i = t; i < 512; i += 256) {
            int half = i >> 8, idx = i & 255, p = idx >> 3, q4 = idx & 7;
            if (half == 0) stf4(&A1 [p*36 + 4*q4], lrelu4(sv[p], ldf4(&tv[4*q4])));
            else           stf4(&A1T[p*36 + 4*q4], lrelu4(tv[p], ldf4(&sv[4*q4])));
        }
    } else {
        int tp = t - 256, j = tp >> 4, k0 = tp & 15;
        float acc0 = 0.f, acc1 = 0.f;
        #pragma unroll
        for (int c4 = 0; c4 < 16; ++c4) {
            float4 w4 = ldf4(&WpT1[j*64 + 4*c4]);
            acc0 += dot4(ldf4(&x1[k0*68 + 4*c4]), w4);
            acc1 += dot4(ldf4(&x1[(k0+16)*68 + 4*c4]), w4);
        }
        P1T[j*36 + k0] = acc0;
        P1T[j*36 + k0+16] = acc1;
    }
    __syncthreads();

    // ---- G1: M1 = S0@A1 (row-dot A1T), 2p x 2k tiles ----
    {
        int k0 = t & 15, p0 = t >> 4;
        float acc[2][2] = {};
        #pragma unroll
        for (int m4 = 0; m4 < 8; ++m4) {
            float4 s0 = ldf4(&S0[p0*36 + 4*m4]);
            float4 s1 = ldf4(&S0[(p0+32)*36 + 4*m4]);
            float4 a0 = ldf4(&A1T[k0*36 + 4*m4]);
            float4 a1 = ldf4(&A1T[(k0+16)*36 + 4*m4]);
            acc[0][0] += dot4(s0,a0); acc[0][1] += dot4(s0,a1);
            acc[1][0] += dot4(s1,a0); acc[1][1] += dot4(s1,a1);
        }
        #pragma unroll
        for (int i = 0; i < 2; ++i)
            #pragma unroll
            for (int j = 0; j < 2; ++j) M1[(p0+32*i)*36 + k0+16*j] = acc[i][j];
    }
    __syncthreads();

    // ---- G1b: S1raw = A1@P1 + b1 (1/thread) ----
    {
        int m = t >> 4, j = t & 15;
        float acc = b1[j];
        #pragma unroll
        for (int k4 = 0; k4 < 8; ++k4)
            acc += dot4(ldf4(&A1[m*36 + 4*k4]), ldf4(&P1T[j*36 + 4*k4]));
        S1[m*20 + j] = acc;
    }
    __syncthreads();

    // ---- G2: facc = A0 + M1@S0^T, 2p x 4q tiles (q lane-fast) ----
    {
        int q0 = t & 15, p0 = t >> 4;
        #pragma unroll
        for (int i = 0; i < 2; ++i)
            #pragma unroll
            for (int j = 0; j < 4; ++j) facc[i][j] = A0[(p0+32*i)*68 + q0+16*j];
        #pragma unroll
        for (int m4 = 0; m4 < 8; ++m4) {
            float4 m1a = ldf4(&M1[p0*36 + 4*m4]);
            float4 m1b = ldf4(&M1[(p0+32)*36 + 4*m4]);
            #pragma unroll
            for (int j = 0; j < 4; ++j) {
                float4 sj = ldf4(&S0[(q0+16*j)*36 + 4*m4]);
                facc[0][j] += dot4(m1a, sj);
                facc[1][j] += dot4(m1b, sj);
            }
        }
    }
    __syncthreads();

    // ---- G2b: softmax S1 rows (4 lanes/row) -> write S1T only ----
    if (t < 128) {
        int m = t >> 2, l = t & 3;
        float4 v = ldf4(&S1[m*20 + 4*l]);
        float mx = vmax4(v);
        mx = fmaxf(mx, __shfl_xor(mx,1)); mx = fmaxf(mx, __shfl_xor(mx,2));
        v = exp4(v, mx);
        float sm = vsum4(v);
        sm += __shfl_xor(sm,1); sm += __shfl_xor(sm,2);
        float inv = 1.f/sm;
        S1T[(4*l+0)*36 + m] = v.x*inv;
        S1T[(4*l+1)*36 + m] = v.y*inv;
        S1T[(4*l+2)*36 + m] = v.z*inv;
        S1T[(4*l+3)*36 + m] = v.w*inv;
    }
    __syncthreads();

    // ---- G3: S01 = S0@S1 (row-dot S1T), 2p x 2j tiles (t<256) || rxa/rsa (t in [256,288)) ----
    if (t < 256) {
        int j0 = t & 7, p0 = t >> 3;
        float acc[2][2] = {};
        #pragma unroll
        for (int m4 = 0; m4 < 8; ++m4) {
            float4 s0 = ldf4(&S0[p0*36 + 4*m4]);
            float4 s1 = ldf4(&S0[(p0+32)*36 + 4*m4]);
            float4 t0 = ldf4(&S1T[j0*36 + 4*m4]);
            float4 t1 = ldf4(&S1T[(j0+8)*36 + 4*m4]);
            acc[0][0] += dot4(s0,t0); acc[0][1] += dot4(s0,t1);
            acc[1][0] += dot4(s1,t0); acc[1][1] += dot4(s1,t1);
        }
        #pragma unroll
        for (int i = 0; i < 2; ++i)
            #pragma unroll
            for (int j = 0; j < 2; ++j) S01[(p0+32*i)*20 + j0+8*j] = acc[i][j];
    } else if (t < 288) {
        int tp = t - 256, j = tp & 15, which = tp >> 4;
        const float* uv = which ? va : ua;
        float acc = 0.f;
        #pragma unroll
        for (int m4 = 0; m4 < 8; ++m4)
            acc += dot4(ldf4(&S1T[j*36 + 4*m4]), ldf4(&uv[4*m4]));
        if (which) rsa[j] = acc; else rxa[j] = acc;
    }
    __syncthreads();

    // ---- G4: A2T[q][p] = lrelu(rxa[p]+rsa[q]) ----
    if (t < 256) {
        int q = t >> 4, p = t & 15;
        A2T[q*20 + p] = lrelu(rxa[p] + rsa[q]);
    }
    __syncthreads();

    // ---- G5: M2 = S01@A2 (row-dot A2T), 2p x 2k tiles (t<256) ----
    if (t < 256) {
        int k0 = t & 7, p0 = t >> 3;
        float acc[2][2] = {};
        #pragma unroll
        for (int m4 = 0; m4 < 4; ++m4) {
            float4 sa = ldf4(&S01[p0*20 + 4*m4]);
            float4 sb = ldf4(&S01[(p0+32)*20 + 4*m4]);
            float4 a0 = ldf4(&A2T[k0*20 + 4*m4]);
            float4 a1 = ldf4(&A2T[(k0+8)*20 + 4*m4]);
            acc[0][0] += dot4(sa,a0); acc[0][1] += dot4(sa,a1);
            acc[1][0] += dot4(sb,a0); acc[1][1] += dot4(sb,a1);
        }
        #pragma unroll
        for (int i = 0; i < 2; ++i)
            #pragma unroll
            for (int j = 0; j < 2; ++j) M2[(p0+32*i)*20 + k0+8*j] = acc[i][j];
    }
    __syncthreads();

    // ---- G6: facc += M2@S01^T; write A0 ----
    {
        int q0 = t & 15, p0 = t >> 4;
        #pragma unroll
        for (int m4 = 0; m4 < 4; ++m4) {
            float4 m2a = ldf4(&M2[p0*20 + 4*m4]);
            float4 m2b = ldf4(&M2[(p0+32)*20 + 4*m4]);
            #pragma unroll
            for (int j = 0; j < 4; ++j) {
                float4 sj = ldf4(&S01[(q0+16*j)*20 + 4*m4]);
                facc[0][j] += dot4(m2a, sj);
                facc[1][j] += dot4(m2b, sj);
            }
        }
        #pragma unroll
        for (int i = 0; i < 2; ++i)
            #pragma unroll
            for (int j = 0; j < 4; ++j) A0[(p0+32*i)*68 + q0+16*j] = facc[i][j];
    }
    __syncthreads();

    // ---- P13: final softmax stats, 8 lanes/row ----
    {
        int p = t >> 3, l = t & 7;
        float4 v1 = ldf4(&A0[p*68 + 4*l]);
        float4 v2 = ldf4(&A0[p*68 + 32 + 4*l]);
        float mx = fmaxf(vmax4(v1), vmax4(v2));
        mx = fmaxf(mx, __shfl_xor(mx,1)); mx = fmaxf(mx, __shfl_xor(mx,2)); mx = fmaxf(mx, __shfl_xor(mx,4));
        float sm = vsum4(exp4(v1,mx)) + vsum4(exp4(v2,mx));
        sm += __shfl_xor(sm,1); sm += __shfl_xor(sm,2); sm += __shfl_xor(sm,4);
        if (l == 0) { sv[p] = mx; tv[p] = 1.f/sm; }
    }
    __syncthreads();

    // ---- P14: write out ----
    for (int i = t; i < 1024; i += 512) {
        int p = i >> 4, q4 = i & 15;
        float mx = sv[p], inv = tv[p];
        float4 a = exp4(ldf4(&A0[p*68 + 4*q4]), mx);
        a.x *= inv; a.y *= inv; a.z *= inv; a.w *= inv;
        stf4(&out[(size_t)g*4096 + p*64 + 4*q4], a);
    }
}

// ================== SPATIAL: 16384 graphs of 25 nodes, 256 threads ==================
__global__ __launch_bounds__(256, 4)
void spatial_kernel(const float* __restrict__ src, const float* __restrict__ wvg,
                    const float* __restrict__ WpT0, const float* __restrict__ WpT1,
                    const float* __restrict__ b0, const float* __restrict__ b1,
                    float* __restrict__ out, int nwg8)
{
    __shared__ __align__(16) float Rx0[1700];   // x0[25][68]; then tenants
    __shared__ __align__(16) float RA0[700];    // A0/fusion [25][28]
    __shared__ __align__(16) float RPR[816];    // P0T[12][28] -> x1[12][68] -> M1[25][20] -> M2[25][12]
    __shared__ __align__(16) float RS0[500];    // S0[25][20]
    __shared__ __align__(16) float sv[32], tv[32], ua[32], va[32], rxa[8], rsa[8];

    float* x0  = Rx0;
    float* A1  = Rx0;          // [12][20]
    float* A1T = Rx0 + 240;    // [12][20]
    float* P1T = Rx0 + 480;    // [5][12]
    float* S1  = Rx0 + 540;    // [12][12]
    float* S1T = Rx0 + 684;    // [5][12]
    float* A2T = Rx0 + 744;    // [5][12]
    float* S01 = Rx0 + 804;    // [25][12]
    float* A0  = RA0;
    float* P0T = RPR;          // [12][28]
    float* x1  = RPR;          // [12][68]
    float* M1  = RPR;          // [25][20]
    float* M2  = RPR;          // [25][12]
    float* S0  = RS0;          // [25][20]

    const int t = threadIdx.x;
    const int g = (blockIdx.x & 7) * nwg8 + (blockIdx.x >> 3);
    const int b = g >> 6, inner = g & 63;
    const float* srcb = src + (size_t)b*102400 + inner*25;  // + c*1600 + r  (inner = timestep, stride 25)

    // ---- L ----
    for (int i = t; i < 400; i += 256) {
        int r = i % 25, c0 = (i / 25) << 2;
        float4 v;
        v.x = srcb[(c0+0)*1600 + r];
        v.y = srcb[(c0+1)*1600 + r];
        v.z = srcb[(c0+2)*1600 + r];
        v.w = srcb[(c0+3)*1600 + r];
        stf4(&x0[r*68 + c0], v);
    }
    __syncthreads();

    // ---- P0: dots || P0T (zero-padded cols 25..27) ----
    if (t < 50) {
        int which = t / 25, p = t - which*25;
        const float* w = wvg + which*64;
        float a = 0.f;
        #pragma unroll
        for (int c4 = 0; c4 < 16; ++c4) a += dot4(ldf4(&x0[p*68 + 4*c4]), ldf4(&w[4*c4]));
        if (which) tv[p] = a; else sv[p] = a;
    }
    for (int i = t; i < 336; i += 256) {
        int k = i / 28, m = i - k*28;
        float a = 0.f;
        if (m < 25) {
            #pragma unroll
            for (int c4 = 0; c4 < 16; ++c4) a += dot4(ldf4(&WpT0[k*64 + 4*c4]), ldf4(&x0[m*68 + 4*c4]));
        }
        P0T[k*28 + m] = a;
    }
    __syncthreads();

    // ---- P1: A0 (pads = -1e30) ----
    for (int i = t; i < 700; i += 256) {
        int p = i / 28, q = i - p*28;
        A0[i] = (q < 25) ? lrelu(sv[p] + tv[q]) : -1e30f;
    }
    __syncthreads();

    // ---- P2: S0raw ----
    for (int i = t; i < 300; i += 256) {
        int p = i / 12, k = i - p*12;
        float acc = b0[k];
        #pragma unroll
        for (int m4 = 0; m4 < 7; ++m4) acc += dot4(ldf4(&A0[p*28 + 4*m4]), ldf4(&P0T[k*28 + 4*m4]));
        S0[p*20 + k] = acc;
    }
    __syncthreads();

    // ---- P3: softmax S0 rows ----
    if (t < 25) {
        float4 r[3]; float mx = -1e30f;
        #pragma unroll
        for (int u = 0; u < 3; ++u) { r[u] = ldf4(&S0[t*20 + 4*u]); mx = fmaxf(mx, vmax4(r[u])); }
        float sm = 0.f;
        #pragma unroll
        for (int u = 0; u < 3; ++u) { r[u] = exp4(r[u], mx); sm += vsum4(r[u]); }
        float inv = 1.f/sm;
        #pragma unroll
        for (int u = 0; u < 3; ++u) {
            r[u].x *= inv; r[u].y *= inv; r[u].z *= inv; r[u].w *= inv;
            stf4(&S0[t*20 + 4*u], r[u]);
        }
    }
    __syncthreads();

    // ---- P4: x1[k][c] ----
    if (t < 96) {
        int k = t >> 3, c0 = (t & 7) << 3;
        float4 a = {0,0,0,0}, bb = {0,0,0,0};
        #pragma unroll
        for (int p = 0; p < 25; ++p) {
            float s = S0[p*20 + k];
            a  = fma4(s, ldf4(&x0[p*68 + c0]), a);
            bb = fma4(s, ldf4(&x0[p*68 + c0 + 4]), bb);
        }
        stf4(&x1[k*68 + c0], a);
        stf4(&x1[k*68 + c0 + 4], bb);
    }
    __syncthreads();

    // ---- P5: dots || P1T ----
    if (t < 48) {
        int which = t / 12, p = t - which*12;
        const float* w = wvg + (2+which)*64;
        float a = 0.f;
        #pragma unroll
        for (int c4 = 0; c4 < 16; ++c4) a += dot4(ldf4(&x1[p*68 + 4*c4]), ldf4(&w[4*c4]));
        if (which == 0) sv[p] = a; else if (which == 1) tv[p] = a;
        else if (which == 2) ua[p] = a; else va[p] = a;
    }
    for (int i = t; i < 60; i += 256) {
        int j = i / 12, k = i - j*12;
        float a = 0.f;
        #pragma unroll
        for (int c4 = 0; c4 < 16; ++c4) a += dot4(ldf4(&WpT1[j*64 + 4*c4]), ldf4(&x1[k*68 + 4*c4]));
        P1T[j*12 + k] = a;
    }
    __syncthreads();

    // ---- P6: A1, A1T ----
    for (int i = t; i < 288; i += 256) {
        int mat = i / 144, rr = (i - mat*144) / 12, q = i % 12;
        if (mat == 0) A1 [rr*20 + q] = lrelu(sv[rr] + tv[q]);
        else          A1T[rr*20 + q] = lrelu(sv[q] + tv[rr]);
    }
    __syncthreads();

    // ---- G1: M1 || S1raw ----
    for (int i = t; i < 300; i += 256) {
        int p = i / 12, k = i - p*12;
        float acc = 0.f;
        #pragma unroll
        for (int m4 = 0; m4 < 3; ++m4) acc += dot4(ldf4(&S0[p*20 + 4*m4]), ldf4(&A1T[k*20 + 4*m4]));
        M1[p*20 + k] = acc;
    }
    for (int i = t; i < 60; i += 256) {
        int m = i / 5, j = i - m*5;
        float acc = b1[j];
        #pragma unroll
        for (int k4 = 0; k4 < 3; ++k4) acc += dot4(ldf4(&A1[m*20 + 4*k4]), ldf4(&P1T[j*12 + 4*k4]));
        S1[m*12 + j] = acc;
    }
    __syncthreads();

    // ---- G2a: softmax S1 || fusion pass1 ----
    if (t < 12) {
        float mx = -1e30f;
        float r0 = S1[t*12+0], r1 = S1[t*12+1], r2 = S1[t*12+2], r3 = S1[t*12+3], r4 = S1[t*12+4];
        mx = fmaxf(fmaxf(fmaxf(r0,r1), fmaxf(r2,r3)), r4);
        r0 = __expf(r0-mx); r1 = __expf(r1-mx); r2 = __expf(r2-mx); r3 = __expf(r3-mx); r4 = __expf(r4-mx);
        float inv = 1.f/(r0+r1+r2+r3+r4);
        S1[t*12+0] = r0*inv; S1[t*12+1] = r1*inv; S1[t*12+2] = r2*inv; S1[t*12+3] = r3*inv; S1[t*12+4] = r4*inv;
    }
    for (int i = t; i < 625; i += 256) {
        int p = i / 25, q = i - p*25;
        float acc = A0[p*28 + q];
        #pragma unroll
        for (int m4 = 0; m4 < 3; ++m4) acc += dot4(ldf4(&M1[p*20 + 4*m4]), ldf4(&S0[q*20 + 4*m4]));
        A0[p*28 + q] = acc;
    }
    __syncthreads();

    // ---- G2b: S1T || rxa/rsa ----
    for (int i = t; i < 60; i += 256) {
        int j = i / 12, m = i - j*12;
        S1T[j*12 + m] = S1[m*12 + j];
    }
    if (t >= 64 && t < 74) {
        int tp = t - 64, which = tp / 5, k = tp - which*5;
        float a = 0.f;
        #pragma unroll
        for (int n = 0; n < 12; ++n) a += S1[n*12 + k] * (which ? va[n] : ua[n]);
        if (which) rsa[k] = a; else rxa[k] = a;
    }
    __syncthreads();

    // ---- G3: A2T (zero-padded) || S01 (zero-padded) ----
    for (int i = t; i < 40; i += 256) {
        int q = i >> 3, p = i & 7;
        A2T[q*12 + p] = (p < 5) ? lrelu(rxa[p] + rsa[q]) : 0.f;
    }
    for (int i = t; i < 200; i += 256) {
        int p = i >> 3, c = i & 7;
        float acc = 0.f;
        if (c < 5) {
            #pragma unroll
            for (int m4 = 0; m4 < 3; ++m4) acc += dot4(ldf4(&S0[p*20 + 4*m4]), ldf4(&S1T[c*12 + 4*m4]));
        }
        S01[p*12 + c] = acc;
    }
    __syncthreads();

    // ---- G4: M2 (zero-padded) ----
    for (int i = t; i < 200; i += 256) {
        int p = i >> 3, k = i & 7;
        float acc = 0.f;
        if (k < 5) {
            #pragma unroll
            for (int m4 = 0; m4 < 2; ++m4) acc += dot4(ldf4(&S01[p*12 + 4*m4]), ldf4(&A2T[k*12 + 4*m4]));
        }
        M2[p*12 + k] = acc;
    }
    __syncthreads();

    // ---- G5: fusion pass2 ----
    for (int i = t; i < 625; i += 256) {
        int p = i / 25, q = i - p*25;
        float acc = A0[p*28 + q];
        #pragma unroll
        for (int m4 = 0; m4 < 2; ++m4) acc += dot4(ldf4(&M2[p*12 + 4*m4]), ldf4(&S01[q*12 + 4*m4]));
        A0[p*28 + q] = acc;
    }
    __syncthreads();

    // ---- P13: stats ----
    if (t < 25) {
        float4 r[7]; float mx = -1e30f;
        #pragma unroll
        for (int u = 0; u < 7; ++u) { r[u] = ldf4(&A0[t*28 + 4*u]); mx = fmaxf(mx, vmax4(r[u])); }
        float sm = 0.f;
        #pragma unroll
        for (int u = 0; u < 7; ++u) sm += vsum4(exp4(r[u], mx));
        sv[t] = mx; tv[t] = 1.f/sm;
    }
    __syncthreads();

    // ---- P14 ----
    for (int i = t; i < 625; i += 256) {
        int p = i / 25, q = i - p*25;
        out[(size_t)g*625 + i] = __expf(A0[p*28 + q] - sv[p]) * tv[p];
    }
}

extern "C" void kernel_launch(void* const* d_in, const int* in_sizes, int n_in,
                              void* d_out, int out_size, void* d_ws, size_t ws_size,
                              hipStream_t stream) {
    const float* src = (const float*)d_in[0];
    const float* W   = (const float*)d_in[1];
    float* ws = (float*)d_ws;

    prep_kernel<<<16, 64, 0, stream>>>(W,
        (const float*)d_in[2],  (const float*)d_in[3],    // as_src0, as_dst0
        (const float*)d_in[6],  (const float*)d_in[7],    // as_src1, as_dst1
        (const float*)d_in[10], (const float*)d_in[11],   // as_src2, as_dst2
        (const float*)d_in[4],  (const float*)d_in[5],    // at_src0, at_dst0
        (const float*)d_in[8],  (const float*)d_in[9],    // at_src1, at_dst1
        (const float*)d_in[12], (const float*)d_in[13],   // at_src2, at_dst2
        (const float*)d_in[14], (const float*)d_in[16],   // Wsp0, Wsp1
        (const float*)d_in[18], (const float*)d_in[20],   // Wtp0, Wtp1
        ws);

    float* out = (float*)d_out;
    spatial_kernel<<<16384, 256, 0, stream>>>(
        src, ws, ws + 768, ws + 1536,
        (const float*)d_in[15], (const float*)d_in[17],
        out, 16384/8);
    temporal_kernel<<<6400, 512, 0, stream>>>(
        src, ws + 384, ws + 1856, ws + 3904,
        (const float*)d_in[19], (const float*)d_in[21],
        out + 10240000, 6400/8);
}